// Round 9
// baseline (327.742 us; speedup 1.0000x reference)
//
#include <hip/hip_runtime.h>
#include <cstdint>
#include <cstddef>

#define PASSA_EDGES 1024

typedef __attribute__((ext_vector_type(8))) short bf16x8;   // 8 bf16 = 4 VGPR (MFMA A/B frag)
typedef __attribute__((ext_vector_type(4))) float f32x4;    // MFMA C/D frag

// ---------------- bf16 helpers ----------------

__device__ __forceinline__ unsigned short f2bf(float f) {  // RNE
    unsigned int u = __float_as_uint(f);
    u += 0x7FFFu + ((u >> 16) & 1u);
    return (unsigned short)(u >> 16);
}
__device__ __forceinline__ float bf2f(unsigned short h) {
    return __uint_as_float((unsigned int)h << 16);
}

// fma 8 bf16 (packed in uint4) * w into acc[8]
__device__ __forceinline__ void bf8_fma(uint4 u, float w, float* acc) {
    acc[0] += __uint_as_float(u.x << 16) * w;
    acc[1] += __uint_as_float(u.x & 0xFFFF0000u) * w;
    acc[2] += __uint_as_float(u.y << 16) * w;
    acc[3] += __uint_as_float(u.y & 0xFFFF0000u) * w;
    acc[4] += __uint_as_float(u.z << 16) * w;
    acc[5] += __uint_as_float(u.z & 0xFFFF0000u) * w;
    acc[6] += __uint_as_float(u.w << 16) * w;
    acc[7] += __uint_as_float(u.w & 0xFFFF0000u) * w;
}
__device__ __forceinline__ void bf8_unpack(uint4 u, float* v) {
    v[0] = __uint_as_float(u.x << 16);
    v[1] = __uint_as_float(u.x & 0xFFFF0000u);
    v[2] = __uint_as_float(u.y << 16);
    v[3] = __uint_as_float(u.y & 0xFFFF0000u);
    v[4] = __uint_as_float(u.z << 16);
    v[5] = __uint_as_float(u.z & 0xFFFF0000u);
    v[6] = __uint_as_float(u.w << 16);
    v[7] = __uint_as_float(u.w & 0xFFFF0000u);
}

// ---------------- pass A v3: scan-free bin into slabs + fused degree hist ----------
// R9: 1024-edge blocks (1564 blocks = 6/CU; R8's 782 capped occupancy at 22%).
// First loop reads dst once and feeds BOTH the LDS bucket count and the global
// per-node degree hist (L2-resident 400 KB; R7 showed these atomics are cheap) --
// this deletes the entire hist_dis kernel (19 MB bbuf re-read + 1.6M LDS atomics).
// bcur is memset-zeroed; slab base t*CAP added here (no bcur_init kernel).

__global__ __launch_bounds__(256) void passA(const int* __restrict__ src,
                                             const int* __restrict__ dst,
                                             int* __restrict__ bcur,
                                             int* __restrict__ hist,
                                             int2* __restrict__ bbuf, int E,
                                             int CAP, int shift) {
    __shared__ int cnt[256], cur[256];
    const int t  = threadIdx.x;
    const int e0 = blockIdx.x * PASSA_EDGES;
    const int n  = min(PASSA_EDGES, E - e0);

    cnt[t] = 0;
    __syncthreads();
    for (int i = t; i < n; i += 256) {
        const int d = dst[e0 + i];
        atomicAdd(&cnt[d >> shift], 1);
        atomicAdd(&hist[d], 1);          // fused global degree count
    }
    __syncthreads();

    const int c = cnt[t];
    cur[t] = (c > 0) ? t * CAP + atomicAdd(&bcur[t], c) : 0;
    __syncthreads();

    for (int i = t; i < n; i += 256) {
        const int d = dst[e0 + i];
        const int s = src[e0 + i];
        const int b = d >> shift;
        const int p = atomicAdd(&cur[b], 1);
        if (p < (b + 1) * CAP) bbuf[p] = make_int2(s, d);  // slab-overflow guard
    }
}

// ---------------- 3-phase exclusive scan of 8-PADDED degrees; dis folded in --------

__global__ __launch_bounds__(256) void scan_partial(const int* __restrict__ hist,
                                                    int* __restrict__ partials,
                                                    float* __restrict__ dis, int N) {
    __shared__ int red[256];
    const int t    = threadIdx.x;
    const int base = blockIdx.x * 1024 + t * 4;
    int s = 0;
    if (base + 3 < N) {
        int4 v = *(const int4*)&hist[base];
        s = ((v.x + 7) & ~7) + ((v.y + 7) & ~7) + ((v.z + 7) & ~7) + ((v.w + 7) & ~7);
        dis[base]     = rsqrtf((float)(v.x + 1));  // +1 self loop
        dis[base + 1] = rsqrtf((float)(v.y + 1));
        dis[base + 2] = rsqrtf((float)(v.z + 1));
        dis[base + 3] = rsqrtf((float)(v.w + 1));
    } else {
        for (int i = 0; i < 4; i++)
            if (base + i < N) {
                int c = hist[base + i];
                s += (c + 7) & ~7;
                dis[base + i] = rsqrtf((float)(c + 1));
            }
    }
    red[t] = s;
    __syncthreads();
    for (int off = 128; off; off >>= 1) {
        if (t < off) red[t] += red[t + off];
        __syncthreads();
    }
    if (t == 0) partials[blockIdx.x] = red[0];
}

__global__ __launch_bounds__(256) void scan_offsets(int* __restrict__ partials, int NB) {
    __shared__ int tmp[256];
    const int t = threadIdx.x;
    int v = (t < NB) ? partials[t] : 0;
    tmp[t] = v;
    __syncthreads();
    for (int off = 1; off < 256; off <<= 1) {
        int u = (t >= off) ? tmp[t - off] : 0;
        __syncthreads();
        tmp[t] += u;
        __syncthreads();
    }
    if (t < NB) partials[t] = tmp[t] - v;
}

__global__ __launch_bounds__(256) void scan_apply(const int* __restrict__ hist,
                                                  const int* __restrict__ partials,
                                                  int* __restrict__ ptr, int N) {
    __shared__ int tsum[256];
    const int t    = threadIdx.x;
    const int base = blockIdx.x * 1024 + t * 4;
    int v[4];
    int s = 0;
    for (int i = 0; i < 4; i++) {
        int c = (base + i < N) ? hist[base + i] : 0;
        v[i]  = (c + 7) & ~7;
        s += v[i];
    }
    tsum[t] = s;
    __syncthreads();
    for (int off = 1; off < 256; off <<= 1) {
        int u = (t >= off) ? tsum[t - off] : 0;
        __syncthreads();
        tsum[t] += u;
        __syncthreads();
    }
    int run = partials[blockIdx.x] + tsum[t] - s;
    for (int i = 0; i < 4; i++) {
        if (base + i < N) {
            ptr[base + i] = run;
            run += v[i];
        }
    }
    if (base <= N - 1 && N - 1 < base + 4) ptr[N] = run;  // total = padded E
}

// ---------------- pass B v3: image-free per-bucket scatter + fused pad fill --------
// LDS node-cursors seeded from ptr; direct global writes land inside the bucket's
// ~100 KB contiguous csrw window -> L2 assembles full lines, no amplification.
// After the scatter barrier lcur[j] == ptr[j]+deg[j], so the <=7 pad slots per row
// ({0,0.0f}: row-0 loads, fma x0) are filled here -- pad_fill kernel deleted.

__global__ __launch_bounds__(256) void passB(const int2* __restrict__ bbuf,
                                             const int* __restrict__ bcur,
                                             const int* __restrict__ ptr,
                                             int2* __restrict__ csrw,
                                             const float* __restrict__ dis,
                                             int N, int CAP, int shift) {
    __shared__ int lcur[1024];
    const int b     = blockIdx.x;
    const int node0 = b << shift;
    const int nn    = min(1 << shift, N - node0);
    for (int j = threadIdx.x; j < nn; j += 256) lcur[j] = ptr[node0 + j];
    __syncthreads();

    const int start = b * CAP;
    const int end   = min(b * CAP + bcur[b], (b + 1) * CAP);
    for (int e = start + threadIdx.x; e < end; e += 256) {
        const int2 pr = bbuf[e];
        const int  p  = atomicAdd(&lcur[pr.y - node0], 1);
        csrw[p] = make_int2(pr.x, __float_as_int(dis[pr.x]));
    }
    __syncthreads();

    for (int j = threadIdx.x; j < nn; j += 256) {
        const int t1 = ptr[node0 + j + 1];
        for (int p = lcur[j]; p < t1; ++p) csrw[p] = make_int2(0, 0);
    }
}

// ---------------- W fragment prep: fp32 W -> fragment-ordered bf16 hi/lo ----------
// B-frag layout for mfma_f32_16x16x32_bf16: lane&15 = out-col n, lane>>4 = k-octet,
// 8 contiguous k per lane. Stored so lane l of frag-block (kstep*4+nt) reads its
// 16 B contiguously at [(kstep*4+nt)*512 + l*8]. hi = RNE(w); lo = RNE(w - hi):
// Xhi*Whi + Xlo*Whi + Xhi*Wlo reproduces fp32 to ~2^-17 (lo*lo dropped).

__global__ __launch_bounds__(256) void prep_wfrag(const float* __restrict__ W1,
                                                  const float* __restrict__ W2,
                                                  unsigned short* __restrict__ whi1,
                                                  unsigned short* __restrict__ wlo1,
                                                  unsigned short* __restrict__ whi2,
                                                  unsigned short* __restrict__ wlo2) {
    for (int e = threadIdx.x; e < 128 * 64; e += 256) {
        const int blk = e >> 9, l = (e >> 3) & 63, j = e & 7;
        const int k = (blk >> 2) * 32 + (l >> 4) * 8 + j;
        const int n = (blk & 3) * 16 + (l & 15);
        const float v = W1[k * 64 + n];
        const unsigned short h = f2bf(v);
        whi1[e] = h;
        wlo1[e] = f2bf(v - bf2f(h));
    }
    for (int e = threadIdx.x; e < 64 * 64; e += 256) {
        const int blk = e >> 9, l = (e >> 3) & 63, j = e & 7;
        const int k = (blk >> 2) * 32 + (l >> 4) * 8 + j;
        const int n = (blk & 3) * 16 + (l & 15);
        const float v = W2[k * 64 + n];
        const unsigned short h = f2bf(v);
        whi2[e] = h;
        wlo2[e] = f2bf(v - bf2f(h));
    }
}

// ---------------- MFMA GEMM: Yb[N x 64](bf16) = X[N x K](f32) @ W[K x 64] ----------
// 64-row tile, 4 waves (wave w owns rows w*16..w*16+15). X staged fp32 into
// padded LDS (LDX=K+4 -> bank-balanced A-frag reads). A-frag: lane&15 = row m,
// lane>>4 = k-octet (8 contiguous k), split to bf16 hi/lo in-register. B-frags:
// coalesced 16 B/lane global loads from the prep arrays (48 KB, L2-hot).
// 3 MFMA per (kstep,ntile) = split-fp32 accuracy.
// C/D: col = lane&15, row = (lane>>4)*4 + reg [m89-verified mapping].

template <int K>
__global__ __launch_bounds__(256) void gemm_mfma(const float* __restrict__ X,
                                                 const unsigned short* __restrict__ whi,
                                                 const unsigned short* __restrict__ wlo,
                                                 unsigned short* __restrict__ Yb, int N) {
    constexpr int LDX = K + 4;
    __shared__ float xs[64 * LDX];
    const int tid  = threadIdx.x;
    const int row0 = blockIdx.x * 64;

#pragma unroll
    for (int i = 0; i < (64 * K) / 1024; ++i) {
        const int fidx = i * 1024 + tid * 4;
        const int r = fidx / K, c = fidx % K;
        const float4 v = *(const float4*)(X + (size_t)min(row0 + r, N - 1) * K + c);
        *(float4*)&xs[r * LDX + c] = v;
    }
    __syncthreads();

    const int w = tid >> 6, l = tid & 63;
    const int m = l & 15, kg = l >> 4;

    f32x4 acc[4] = {};
    const float* xrow = &xs[(w * 16 + m) * LDX];

#pragma unroll
    for (int s = 0; s < K / 32; ++s) {
        const float4 a0 = *(const float4*)(xrow + s * 32 + kg * 8);
        const float4 a1 = *(const float4*)(xrow + s * 32 + kg * 8 + 4);
        const float av[8] = {a0.x, a0.y, a0.z, a0.w, a1.x, a1.y, a1.z, a1.w};
        bf16x8 ahi, alo;
#pragma unroll
        for (int j = 0; j < 8; ++j) {
            const unsigned short h = f2bf(av[j]);
            ahi[j] = (short)h;
            alo[j] = (short)f2bf(av[j] - bf2f(h));
        }
#pragma unroll
        for (int nt = 0; nt < 4; ++nt) {
            const bf16x8 bh = *(const bf16x8*)&whi[(s * 4 + nt) * 512 + l * 8];
            const bf16x8 bl = *(const bf16x8*)&wlo[(s * 4 + nt) * 512 + l * 8];
            acc[nt] = __builtin_amdgcn_mfma_f32_16x16x32_bf16(ahi, bh, acc[nt], 0, 0, 0);
            acc[nt] = __builtin_amdgcn_mfma_f32_16x16x32_bf16(alo, bh, acc[nt], 0, 0, 0);
            acc[nt] = __builtin_amdgcn_mfma_f32_16x16x32_bf16(ahi, bl, acc[nt], 0, 0, 0);
        }
    }

#pragma unroll
    for (int nt = 0; nt < 4; ++nt)
#pragma unroll
        for (int r = 0; r < 4; ++r) {
            const int row = row0 + w * 16 + kg * 4 + r;
            if (row < N) Yb[(size_t)row * 64 + nt * 16 + m] = f2bf(acc[nt][r]);
        }
}

// ---------------- shuffle-free oct-row gather: 8 rows/wave, group-per-row ----------
// Row slabs are 8-padded (s0 % 8 == 0), so each lane loads its group's whole
// (src,w) chunk directly as 4 x int4 (64B, all 8 group lanes hit the same L1
// lines -> broadcast). No ds_bpermute, no bounds predication in the loop.
// Next chunk is prefetched one iteration ahead; 8 independent B-row loads are
// in flight per lane per iteration. Groups exit independently (divergence safe).

__device__ __forceinline__ void gather8_pad(const unsigned short* __restrict__ B,
                                            const int2* __restrict__ csrw,
                                            int s0, int iters, int co, float* acc) {
    const int4* cs = (const int4*)(csrw + s0);  // 64B-aligned (s0 % 8 == 0)
    int4 c0 = make_int4(0, 0, 0, 0), c1 = c0, c2 = c0, c3 = c0;
    if (iters > 0) { c0 = cs[0]; c1 = cs[1]; c2 = cs[2]; c3 = cs[3]; }
    for (int it = 0; it < iters; ++it) {
        const int nb = min(it + 1, iters - 1) * 4;   // prefetch next chunk (clamped)
        int4 n0 = cs[nb], n1 = cs[nb + 1], n2 = cs[nb + 2], n3 = cs[nb + 3];
        uint4 u0 = *(const uint4*)&B[(size_t)c0.x * 64 + co * 8];
        uint4 u1 = *(const uint4*)&B[(size_t)c0.z * 64 + co * 8];
        uint4 u2 = *(const uint4*)&B[(size_t)c1.x * 64 + co * 8];
        uint4 u3 = *(const uint4*)&B[(size_t)c1.z * 64 + co * 8];
        uint4 u4 = *(const uint4*)&B[(size_t)c2.x * 64 + co * 8];
        uint4 u5 = *(const uint4*)&B[(size_t)c2.z * 64 + co * 8];
        uint4 u6 = *(const uint4*)&B[(size_t)c3.x * 64 + co * 8];
        uint4 u7 = *(const uint4*)&B[(size_t)c3.z * 64 + co * 8];
        bf8_fma(u0, __int_as_float(c0.y), acc);
        bf8_fma(u1, __int_as_float(c0.w), acc);
        bf8_fma(u2, __int_as_float(c1.y), acc);
        bf8_fma(u3, __int_as_float(c1.w), acc);
        bf8_fma(u4, __int_as_float(c2.y), acc);
        bf8_fma(u5, __int_as_float(c2.w), acc);
        bf8_fma(u6, __int_as_float(c3.y), acc);
        bf8_fma(u7, __int_as_float(c3.w), acc);
        c0 = n0; c1 = n1; c2 = n2; c3 = n3;
    }
}

// ---------------- layer 1: pure gather + relu -> f32 h (scratch = d_out) -----------

__global__ __launch_bounds__(256) void agg_l1(const unsigned short* __restrict__ B,
                                              const int2* __restrict__ csrw,
                                              const int* __restrict__ ptr,
                                              const float* __restrict__ dis,
                                              const float* __restrict__ b1,
                                              float* __restrict__ hs, int N) {
    const int wid  = threadIdx.x >> 6;
    const int lane = threadIdx.x & 63;
    const int eg   = lane >> 3;
    const int co   = lane & 7;

    const int  row = blockIdx.x * 32 + wid * 8 + eg;   // group eg owns this row
    const bool hr  = (row < N);

    const int   s0 = hr ? ptr[row] : 0;
    const int   s1 = hr ? ptr[row + 1] : 0;
    const float di = hr ? dis[row] : 0.f;
    const int   iters = (s1 - s0) >> 3;   // slabs are 8-padded

    float acc[8] = {};
    gather8_pad(B, csrw, s0, iters, co, acc);

    if (!hr) return;

    uint4 us = *(const uint4*)&B[(size_t)row * 64 + co * 8];
    float bs[8];
    bf8_unpack(us, bs);
    float bb[8];
    *(float4*)&bb[0] = *(const float4*)&b1[co * 8];
    *(float4*)&bb[4] = *(const float4*)&b1[co * 8 + 4];

    float h[8];
#pragma unroll
    for (int i = 0; i < 8; i++)
        h[i] = fmaxf((acc[i] + bs[i] * di) * di + bb[i], 0.f);

    *(float4*)&hs[(size_t)row * 64 + co * 8]     = make_float4(h[0], h[1], h[2], h[3]);
    *(float4*)&hs[(size_t)row * 64 + co * 8 + 4] = make_float4(h[4], h[5], h[6], h[7]);
}

// ---------------- layer 2: gather h2 + bias + log_softmax -> fp32 out --------------

__global__ __launch_bounds__(256) void agg_l2(const unsigned short* __restrict__ B,
                                              const int2* __restrict__ csrw,
                                              const int* __restrict__ ptr,
                                              const float* __restrict__ dis,
                                              const float* __restrict__ b2,
                                              float* __restrict__ out, int N) {
    const int wid  = threadIdx.x >> 6;
    const int lane = threadIdx.x & 63;
    const int eg   = lane >> 3;
    const int co   = lane & 7;

    const int  row = blockIdx.x * 32 + wid * 8 + eg;
    const bool hr  = (row < N);

    const int   s0 = hr ? ptr[row] : 0;
    const int   s1 = hr ? ptr[row + 1] : 0;
    const float di = hr ? dis[row] : 0.f;
    const int   iters = (s1 - s0) >> 3;

    float acc[8] = {};
    gather8_pad(B, csrw, s0, iters, co, acc);

    if (!hr) return;

    uint4 us = *(const uint4*)&B[(size_t)row * 64 + co * 8];
    float bs[8];
    bf8_unpack(us, bs);
    float bb[8];
    *(float4*)&bb[0] = *(const float4*)&b2[co * 8];
    *(float4*)&bb[4] = *(const float4*)&b2[co * 8 + 4];

    float v[8];
#pragma unroll
    for (int i = 0; i < 8; i++) v[i] = (acc[i] + bs[i] * di) * di + bb[i];

    float m = v[0];
#pragma unroll
    for (int i = 1; i < 8; i++) m = fmaxf(m, v[i]);
#pragma unroll
    for (int off = 1; off <= 4; off <<= 1) m = fmaxf(m, __shfl_xor(m, off));
    float s = 0.f;
#pragma unroll
    for (int i = 0; i < 8; i++) s += __expf(v[i] - m);
#pragma unroll
    for (int off = 1; off <= 4; off <<= 1) s += __shfl_xor(s, off);
    float lse = m + __logf(s);

    float4 oa = make_float4(v[0] - lse, v[1] - lse, v[2] - lse, v[3] - lse);
    float4 ob = make_float4(v[4] - lse, v[5] - lse, v[6] - lse, v[7] - lse);
    *(float4*)&out[(size_t)row * 64 + co * 8]     = oa;
    *(float4*)&out[(size_t)row * 64 + co * 8 + 4] = ob;
}

// ---------------- launch ----------------

extern "C" void kernel_launch(void* const* d_in, const int* in_sizes, int n_in,
                              void* d_out, int out_size, void* d_ws, size_t ws_size,
                              hipStream_t stream) {
    const float* x   = (const float*)d_in[0];
    const int*   ei  = (const int*)d_in[1];
    const float* W1  = (const float*)d_in[2];
    const float* b1  = (const float*)d_in[3];
    const float* W2  = (const float*)d_in[4];
    const float* b2  = (const float*)d_in[5];
    float*       out = (float*)d_out;

    const int  N   = in_sizes[0] / 128;
    const int  E   = in_sizes[1] / 2;
    const int* src = ei;
    const int* dst = ei + E;
    const int  NB  = (N + 1023) / 1024;

    int shift = 9;
    while (((N - 1) >> shift) >= 256) shift++;
    const int NBUCK = ((N - 1) >> shift) + 1;
    const int CAP   = ((E / NBUCK) * 3 / 2 + 255) & ~255;

    auto align256 = [](size_t v) { return (v + 255) & ~(size_t)255; };
    char*           p        = (char*)d_ws;
    float*          dis      = (float*)p;          p += align256((size_t)N * 4);
    int*            ptr      = (int*)p;            p += align256((size_t)(N + 1) * 4);
    int*            hist     = (int*)p;            p += align256((size_t)N * 4);
    int*            partials = (int*)p;            p += align256((size_t)NB * 4);
    int*            bcur     = (int*)p;            p += align256(256 * 4);
    int2*           csrw     = (int2*)p;           p += align256(((size_t)E + 8 * (size_t)N) * 8);
    int2*           bbuf     = (int2*)p;           p += align256((size_t)NBUCK * CAP * 8);
    unsigned short* xwb      = (unsigned short*)p; p += align256((size_t)N * 64 * 2);
    unsigned short* whi1     = (unsigned short*)p; p += align256(128 * 64 * 2);
    unsigned short* wlo1     = (unsigned short*)p; p += align256(128 * 64 * 2);
    unsigned short* whi2     = (unsigned short*)p; p += align256(64 * 64 * 2);
    unsigned short* wlo2     = (unsigned short*)p; p += align256(64 * 64 * 2);

    // h (post-relu, f32) scratch lives in d_out: dead until agg_l2 overwrites it.
    float* hs = out;

    hipMemsetAsync(hist, 0, (size_t)N * 4, stream);   // degree counters
    hipMemsetAsync(bcur, 0, 256 * 4, stream);         // within-slab cursors
    prep_wfrag<<<1, 256, 0, stream>>>(W1, W2, whi1, wlo1, whi2, wlo2);
    passA<<<(E + PASSA_EDGES - 1) / PASSA_EDGES, 256, 0, stream>>>(src, dst, bcur, hist, bbuf, E, CAP, shift);
    scan_partial<<<NB, 256, 0, stream>>>(hist, partials, dis, N);
    scan_offsets<<<1, 256, 0, stream>>>(partials, NB);
    scan_apply<<<NB, 256, 0, stream>>>(hist, partials, ptr, N);
    passB<<<NBUCK, 256, 0, stream>>>(bbuf, bcur, ptr, csrw, dis, N, CAP, shift);

    gemm_mfma<128><<<(N + 63) / 64, 256, 0, stream>>>(x, whi1, wlo1, xwb, N);
    agg_l1<<<(N + 31) / 32, 256, 0, stream>>>(xwb, csrw, ptr, dis, b1, hs, N);
    // gemm2: h2(bf16, reuses dead xwb) = h(f32, in d_out) @ W2
    gemm_mfma<64><<<(N + 63) / 64, 256, 0, stream>>>(hs, whi2, wlo2, xwb, N);
    agg_l2<<<(N + 31) / 32, 256, 0, stream>>>(xwb, csrw, ptr, dis, b2, out, N);
}

// Round 10
// 272.498 us; speedup vs baseline: 1.2027x; 1.2027x over previous
//
#include <hip/hip_runtime.h>
#include <cstdint>
#include <cstddef>

#define PASSA_EDGES 1024

typedef __attribute__((ext_vector_type(8))) short bf16x8;   // 8 bf16 = 4 VGPR (MFMA A/B frag)
typedef __attribute__((ext_vector_type(4))) float f32x4;    // MFMA C/D frag

// ---------------- bf16 helpers ----------------

__device__ __forceinline__ unsigned short f2bf(float f) {  // RNE
    unsigned int u = __float_as_uint(f);
    u += 0x7FFFu + ((u >> 16) & 1u);
    return (unsigned short)(u >> 16);
}
__device__ __forceinline__ float bf2f(unsigned short h) {
    return __uint_as_float((unsigned int)h << 16);
}

// acc[8] += 8 bf16 (packed in uint4)  -- weight-free gather accumulate
__device__ __forceinline__ void bf8_acc(uint4 u, float* acc) {
    acc[0] += __uint_as_float(u.x << 16);
    acc[1] += __uint_as_float(u.x & 0xFFFF0000u);
    acc[2] += __uint_as_float(u.y << 16);
    acc[3] += __uint_as_float(u.y & 0xFFFF0000u);
    acc[4] += __uint_as_float(u.z << 16);
    acc[5] += __uint_as_float(u.z & 0xFFFF0000u);
    acc[6] += __uint_as_float(u.w << 16);
    acc[7] += __uint_as_float(u.w & 0xFFFF0000u);
}
__device__ __forceinline__ void bf8_unpack(uint4 u, float* v) {
    v[0] = __uint_as_float(u.x << 16);
    v[1] = __uint_as_float(u.x & 0xFFFF0000u);
    v[2] = __uint_as_float(u.y << 16);
    v[3] = __uint_as_float(u.y & 0xFFFF0000u);
    v[4] = __uint_as_float(u.z << 16);
    v[5] = __uint_as_float(u.z & 0xFFFF0000u);
    v[6] = __uint_as_float(u.w << 16);
    v[7] = __uint_as_float(u.w & 0xFFFF0000u);
}

// ---------------- pass A (R8 form @1024 edges): scan-free bin into slabs -----------
// R10: NO fused global hist (R9: random 4B global atomics cost ~64B of RMW traffic
// each -> +52MB WRITE_SIZE, 102us). LDS-only counting; 1563 blocks = 6/CU (R9
// proved the shape: 57% occ, VALU 0.8%). bcur memset-zeroed; slab base t*CAP here.

__global__ __launch_bounds__(256) void passA(const int* __restrict__ src,
                                             const int* __restrict__ dst,
                                             int* __restrict__ bcur,
                                             int2* __restrict__ bbuf, int E,
                                             int CAP, int shift) {
    __shared__ int cnt[256], cur[256];
    const int t  = threadIdx.x;
    const int e0 = blockIdx.x * PASSA_EDGES;
    const int n  = min(PASSA_EDGES, E - e0);

    cnt[t] = 0;
    __syncthreads();
    for (int i = t; i < n; i += 256) atomicAdd(&cnt[dst[e0 + i] >> shift], 1);
    __syncthreads();

    const int c = cnt[t];
    cur[t] = (c > 0) ? t * CAP + atomicAdd(&bcur[t], c) : 0;
    __syncthreads();

    for (int i = t; i < n; i += 256) {
        const int d = dst[e0 + i];
        const int s = src[e0 + i];
        const int b = d >> shift;
        const int p = atomicAdd(&cur[b], 1);
        if (p < (b + 1) * CAP) bbuf[p] = make_int2(s, d);  // slab-overflow guard
    }
}

// ---------------- per-bucket histogram: TRUE degree (padding applied in scan) ------

__global__ __launch_bounds__(256) void hist_dis(const int2* __restrict__ bbuf,
                                                const int* __restrict__ bcur,
                                                int* __restrict__ hist,
                                                int N, int CAP, int shift) {
    __shared__ int cnt[1024];
    const int b     = blockIdx.x;
    const int node0 = b << shift;
    const int nn    = min(1 << shift, N - node0);
    for (int j = threadIdx.x; j < nn; j += 256) cnt[j] = 0;
    __syncthreads();
    const int start = b * CAP;
    const int end   = min(b * CAP + bcur[b], (b + 1) * CAP);
    for (int e = start + threadIdx.x; e < end; e += 256)
        atomicAdd(&cnt[bbuf[e].y - node0], 1);
    __syncthreads();
    for (int j = threadIdx.x; j < nn; j += 256) hist[node0 + j] = cnt[j];
}

// ---------------- 3-phase exclusive scan of 8-PADDED degrees; dis folded in --------

__global__ __launch_bounds__(256) void scan_partial(const int* __restrict__ hist,
                                                    int* __restrict__ partials,
                                                    float* __restrict__ dis, int N) {
    __shared__ int red[256];
    const int t    = threadIdx.x;
    const int base = blockIdx.x * 1024 + t * 4;
    int s = 0;
    if (base + 3 < N) {
        int4 v = *(const int4*)&hist[base];
        s = ((v.x + 7) & ~7) + ((v.y + 7) & ~7) + ((v.z + 7) & ~7) + ((v.w + 7) & ~7);
        dis[base]     = rsqrtf((float)(v.x + 1));  // +1 self loop
        dis[base + 1] = rsqrtf((float)(v.y + 1));
        dis[base + 2] = rsqrtf((float)(v.z + 1));
        dis[base + 3] = rsqrtf((float)(v.w + 1));
    } else {
        for (int i = 0; i < 4; i++)
            if (base + i < N) {
                int c = hist[base + i];
                s += (c + 7) & ~7;
                dis[base + i] = rsqrtf((float)(c + 1));
            }
    }
    red[t] = s;
    __syncthreads();
    for (int off = 128; off; off >>= 1) {
        if (t < off) red[t] += red[t + off];
        __syncthreads();
    }
    if (t == 0) partials[blockIdx.x] = red[0];
}

__global__ __launch_bounds__(256) void scan_offsets(int* __restrict__ partials, int NB) {
    __shared__ int tmp[256];
    const int t = threadIdx.x;
    int v = (t < NB) ? partials[t] : 0;
    tmp[t] = v;
    __syncthreads();
    for (int off = 1; off < 256; off <<= 1) {
        int u = (t >= off) ? tmp[t - off] : 0;
        __syncthreads();
        tmp[t] += u;
        __syncthreads();
    }
    if (t < NB) partials[t] = tmp[t] - v;
}

__global__ __launch_bounds__(256) void scan_apply(const int* __restrict__ hist,
                                                  const int* __restrict__ partials,
                                                  int* __restrict__ ptr, int N) {
    __shared__ int tsum[256];
    const int t    = threadIdx.x;
    const int base = blockIdx.x * 1024 + t * 4;
    int v[4];
    int s = 0;
    for (int i = 0; i < 4; i++) {
        int c = (base + i < N) ? hist[base + i] : 0;
        v[i]  = (c + 7) & ~7;
        s += v[i];
    }
    tsum[t] = s;
    __syncthreads();
    for (int off = 1; off < 256; off <<= 1) {
        int u = (t >= off) ? tsum[t - off] : 0;
        __syncthreads();
        tsum[t] += u;
        __syncthreads();
    }
    int run = partials[blockIdx.x] + tsum[t] - s;
    for (int i = 0; i < 4; i++) {
        if (base + i < N) {
            ptr[base + i] = run;
            run += v[i];
        }
    }
    if (base <= N - 1 && N - 1 < base + 4) ptr[N] = run;  // total = padded E
}

// ---------------- pass B v4: weight-free scatter -> int csr + fused pad fill -------
// R10: csr entries are src indices ONLY (4 B/edge -- halves write traffic and the
// agg slab reads; dis[src] folded into the GEMM epilogue as a row prescale). Pad
// slots (<=7/row) point at zero-row N of the prescaled table -> contribute 0.
// Direct writes land in the bucket's contiguous window -> no amplification (R7/R9
// lesson: random global writes cost a full 64B line each).

__global__ __launch_bounds__(256) void passB(const int2* __restrict__ bbuf,
                                             const int* __restrict__ bcur,
                                             const int* __restrict__ ptr,
                                             int* __restrict__ csr,
                                             int N, int CAP, int shift) {
    __shared__ int lcur[1024];
    const int b     = blockIdx.x;
    const int node0 = b << shift;
    const int nn    = min(1 << shift, N - node0);
    for (int j = threadIdx.x; j < nn; j += 256) lcur[j] = ptr[node0 + j];
    __syncthreads();

    const int start = b * CAP;
    const int end   = min(b * CAP + bcur[b], (b + 1) * CAP);
    for (int e = start + threadIdx.x; e < end; e += 256) {
        const int2 pr = bbuf[e];
        const int  p  = atomicAdd(&lcur[pr.y - node0], 1);
        csr[p] = pr.x;
    }
    __syncthreads();

    for (int j = threadIdx.x; j < nn; j += 256) {
        const int t1 = ptr[node0 + j + 1];
        for (int p = lcur[j]; p < t1; ++p) csr[p] = N;   // zero-row pad
    }
}

// ---------------- W fragment prep: fp32 W -> fragment-ordered bf16 hi/lo ----------
// B-frag layout for mfma_f32_16x16x32_bf16: lane&15 = out-col n, lane>>4 = k-octet,
// 8 contiguous k per lane. Stored so lane l of frag-block (kstep*4+nt) reads its
// 16 B contiguously at [(kstep*4+nt)*512 + l*8]. hi = RNE(w); lo = RNE(w - hi):
// Xhi*Whi + Xlo*Whi + Xhi*Wlo reproduces fp32 to ~2^-17 (lo*lo dropped).

__global__ __launch_bounds__(256) void prep_wfrag(const float* __restrict__ W1,
                                                  const float* __restrict__ W2,
                                                  unsigned short* __restrict__ whi1,
                                                  unsigned short* __restrict__ wlo1,
                                                  unsigned short* __restrict__ whi2,
                                                  unsigned short* __restrict__ wlo2) {
    for (int e = threadIdx.x; e < 128 * 64; e += 256) {
        const int blk = e >> 9, l = (e >> 3) & 63, j = e & 7;
        const int k = (blk >> 2) * 32 + (l >> 4) * 8 + j;
        const int n = (blk & 3) * 16 + (l & 15);
        const float v = W1[k * 64 + n];
        const unsigned short h = f2bf(v);
        whi1[e] = h;
        wlo1[e] = f2bf(v - bf2f(h));
    }
    for (int e = threadIdx.x; e < 64 * 64; e += 256) {
        const int blk = e >> 9, l = (e >> 3) & 63, j = e & 7;
        const int k = (blk >> 2) * 32 + (l >> 4) * 8 + j;
        const int n = (blk & 3) * 16 + (l & 15);
        const float v = W2[k * 64 + n];
        const unsigned short h = f2bf(v);
        whi2[e] = h;
        wlo2[e] = f2bf(v - bf2f(h));
    }
}

// ---------------- MFMA GEMM: Yb[N x 64](bf16) = (X[N x K](f32) @ W) * dis[row] -----
// R10: dis[row] prescale in the epilogue (f32 multiply before the bf16 round --
// same rounding count as before; enables the weight-free int csr). Rest as R5:
// 64-row tile, 4 waves; X staged fp32 in padded LDS; A split bf16 hi/lo in-reg;
// B-frags coalesced from prep arrays; 3 MFMA per (kstep,ntile) = split-fp32.
// C/D: col = lane&15, row = (lane>>4)*4 + reg [m89-verified mapping].

template <int K>
__global__ __launch_bounds__(256) void gemm_mfma(const float* __restrict__ X,
                                                 const unsigned short* __restrict__ whi,
                                                 const unsigned short* __restrict__ wlo,
                                                 const float* __restrict__ dis,
                                                 unsigned short* __restrict__ Yb, int N) {
    constexpr int LDX = K + 4;
    __shared__ float xs[64 * LDX];
    const int tid  = threadIdx.x;
    const int row0 = blockIdx.x * 64;

#pragma unroll
    for (int i = 0; i < (64 * K) / 1024; ++i) {
        const int fidx = i * 1024 + tid * 4;
        const int r = fidx / K, c = fidx % K;
        const float4 v = *(const float4*)(X + (size_t)min(row0 + r, N - 1) * K + c);
        *(float4*)&xs[r * LDX + c] = v;
    }
    __syncthreads();

    const int w = tid >> 6, l = tid & 63;
    const int m = l & 15, kg = l >> 4;

    f32x4 acc[4] = {};
    const float* xrow = &xs[(w * 16 + m) * LDX];

#pragma unroll
    for (int s = 0; s < K / 32; ++s) {
        const float4 a0 = *(const float4*)(xrow + s * 32 + kg * 8);
        const float4 a1 = *(const float4*)(xrow + s * 32 + kg * 8 + 4);
        const float av[8] = {a0.x, a0.y, a0.z, a0.w, a1.x, a1.y, a1.z, a1.w};
        bf16x8 ahi, alo;
#pragma unroll
        for (int j = 0; j < 8; ++j) {
            const unsigned short h = f2bf(av[j]);
            ahi[j] = (short)h;
            alo[j] = (short)f2bf(av[j] - bf2f(h));
        }
#pragma unroll
        for (int nt = 0; nt < 4; ++nt) {
            const bf16x8 bh = *(const bf16x8*)&whi[(s * 4 + nt) * 512 + l * 8];
            const bf16x8 bl = *(const bf16x8*)&wlo[(s * 4 + nt) * 512 + l * 8];
            acc[nt] = __builtin_amdgcn_mfma_f32_16x16x32_bf16(ahi, bh, acc[nt], 0, 0, 0);
            acc[nt] = __builtin_amdgcn_mfma_f32_16x16x32_bf16(alo, bh, acc[nt], 0, 0, 0);
            acc[nt] = __builtin_amdgcn_mfma_f32_16x16x32_bf16(ahi, bl, acc[nt], 0, 0, 0);
        }
    }

    float dv[4];
#pragma unroll
    for (int r = 0; r < 4; ++r)
        dv[r] = dis[min(row0 + w * 16 + kg * 4 + r, N - 1)];

#pragma unroll
    for (int nt = 0; nt < 4; ++nt)
#pragma unroll
        for (int r = 0; r < 4; ++r) {
            const int row = row0 + w * 16 + kg * 4 + r;
            if (row < N) Yb[(size_t)row * 64 + nt * 16 + m] = f2bf(acc[nt][r] * dv[r]);
        }
}

// ---------------- weight-free oct-row gather: 8 rows/wave, group-per-row -----------
// Slabs 8-padded; each lane reads its group's 8 src indices as 2 x int4 (32 B,
// broadcast across the 8 group lanes) then 8 independent prescaled-B row loads.
// Pad entries index zero-row N (contribute 0). Next chunk prefetched one iteration
// ahead; groups exit independently.

__device__ __forceinline__ void gather8i(const unsigned short* __restrict__ B,
                                         const int* __restrict__ csr,
                                         int s0, int iters, int co, float* acc) {
    const int4* cs = (const int4*)(csr + s0);   // 32B-aligned (s0 % 8 == 0)
    int4 c0 = make_int4(0, 0, 0, 0), c1 = c0;
    if (iters > 0) { c0 = cs[0]; c1 = cs[1]; }
    for (int it = 0; it < iters; ++it) {
        const int nb = min(it + 1, iters - 1) * 2;   // prefetch next chunk (clamped)
        int4 n0 = cs[nb], n1 = cs[nb + 1];
        uint4 u0 = *(const uint4*)&B[(size_t)c0.x * 64 + co * 8];
        uint4 u1 = *(const uint4*)&B[(size_t)c0.y * 64 + co * 8];
        uint4 u2 = *(const uint4*)&B[(size_t)c0.z * 64 + co * 8];
        uint4 u3 = *(const uint4*)&B[(size_t)c0.w * 64 + co * 8];
        uint4 u4 = *(const uint4*)&B[(size_t)c1.x * 64 + co * 8];
        uint4 u5 = *(const uint4*)&B[(size_t)c1.y * 64 + co * 8];
        uint4 u6 = *(const uint4*)&B[(size_t)c1.z * 64 + co * 8];
        uint4 u7 = *(const uint4*)&B[(size_t)c1.w * 64 + co * 8];
        bf8_acc(u0, acc);
        bf8_acc(u1, acc);
        bf8_acc(u2, acc);
        bf8_acc(u3, acc);
        bf8_acc(u4, acc);
        bf8_acc(u5, acc);
        bf8_acc(u6, acc);
        bf8_acc(u7, acc);
        c0 = n0; c1 = n1;
    }
}

// ---------------- layer 1: gather prescaled B + relu -> f32 h (scratch = d_out) ----
// result = (sum B'[e] + B'[row]) * dis[row] + b1  (B' rows already carry dis[src])

__global__ __launch_bounds__(256) void agg_l1(const unsigned short* __restrict__ B,
                                              const int* __restrict__ csr,
                                              const int* __restrict__ ptr,
                                              const float* __restrict__ dis,
                                              const float* __restrict__ b1,
                                              float* __restrict__ hs, int N) {
    const int wid  = threadIdx.x >> 6;
    const int lane = threadIdx.x & 63;
    const int eg   = lane >> 3;
    const int co   = lane & 7;

    const int  row = blockIdx.x * 32 + wid * 8 + eg;   // group eg owns this row
    const bool hr  = (row < N);

    const int   s0 = hr ? ptr[row] : 0;
    const int   s1 = hr ? ptr[row + 1] : 0;
    const float di = hr ? dis[row] : 0.f;
    const int   iters = (s1 - s0) >> 3;   // slabs are 8-padded

    float acc[8] = {};
    gather8i(B, csr, s0, iters, co, acc);

    if (!hr) return;

    uint4 us = *(const uint4*)&B[(size_t)row * 64 + co * 8];
    float bs[8];
    bf8_unpack(us, bs);
    float bb[8];
    *(float4*)&bb[0] = *(const float4*)&b1[co * 8];
    *(float4*)&bb[4] = *(const float4*)&b1[co * 8 + 4];

    float h[8];
#pragma unroll
    for (int i = 0; i < 8; i++)
        h[i] = fmaxf((acc[i] + bs[i]) * di + bb[i], 0.f);

    *(float4*)&hs[(size_t)row * 64 + co * 8]     = make_float4(h[0], h[1], h[2], h[3]);
    *(float4*)&hs[(size_t)row * 64 + co * 8 + 4] = make_float4(h[4], h[5], h[6], h[7]);
}

// ---------------- layer 2: gather prescaled h2 + bias + log_softmax -> fp32 out ----

__global__ __launch_bounds__(256) void agg_l2(const unsigned short* __restrict__ B,
                                              const int* __restrict__ csr,
                                              const int* __restrict__ ptr,
                                              const float* __restrict__ dis,
                                              const float* __restrict__ b2,
                                              float* __restrict__ out, int N) {
    const int wid  = threadIdx.x >> 6;
    const int lane = threadIdx.x & 63;
    const int eg   = lane >> 3;
    const int co   = lane & 7;

    const int  row = blockIdx.x * 32 + wid * 8 + eg;
    const bool hr  = (row < N);

    const int   s0 = hr ? ptr[row] : 0;
    const int   s1 = hr ? ptr[row + 1] : 0;
    const float di = hr ? dis[row] : 0.f;
    const int   iters = (s1 - s0) >> 3;

    float acc[8] = {};
    gather8i(B, csr, s0, iters, co, acc);

    if (!hr) return;

    uint4 us = *(const uint4*)&B[(size_t)row * 64 + co * 8];
    float bs[8];
    bf8_unpack(us, bs);
    float bb[8];
    *(float4*)&bb[0] = *(const float4*)&b2[co * 8];
    *(float4*)&bb[4] = *(const float4*)&b2[co * 8 + 4];

    float v[8];
#pragma unroll
    for (int i = 0; i < 8; i++) v[i] = (acc[i] + bs[i]) * di + bb[i];

    float m = v[0];
#pragma unroll
    for (int i = 1; i < 8; i++) m = fmaxf(m, v[i]);
#pragma unroll
    for (int off = 1; off <= 4; off <<= 1) m = fmaxf(m, __shfl_xor(m, off));
    float s = 0.f;
#pragma unroll
    for (int i = 0; i < 8; i++) s += __expf(v[i] - m);
#pragma unroll
    for (int off = 1; off <= 4; off <<= 1) s += __shfl_xor(s, off);
    float lse = m + __logf(s);

    float4 oa = make_float4(v[0] - lse, v[1] - lse, v[2] - lse, v[3] - lse);
    float4 ob = make_float4(v[4] - lse, v[5] - lse, v[6] - lse, v[7] - lse);
    *(float4*)&out[(size_t)row * 64 + co * 8]     = oa;
    *(float4*)&out[(size_t)row * 64 + co * 8 + 4] = ob;
}

// ---------------- launch ----------------

extern "C" void kernel_launch(void* const* d_in, const int* in_sizes, int n_in,
                              void* d_out, int out_size, void* d_ws, size_t ws_size,
                              hipStream_t stream) {
    const float* x   = (const float*)d_in[0];
    const int*   ei  = (const int*)d_in[1];
    const float* W1  = (const float*)d_in[2];
    const float* b1  = (const float*)d_in[3];
    const float* W2  = (const float*)d_in[4];
    const float* b2  = (const float*)d_in[5];
    float*       out = (float*)d_out;

    const int  N   = in_sizes[0] / 128;
    const int  E   = in_sizes[1] / 2;
    const int* src = ei;
    const int* dst = ei + E;
    const int  NB  = (N + 1023) / 1024;

    int shift = 9;
    while (((N - 1) >> shift) >= 256) shift++;
    const int NBUCK = ((N - 1) >> shift) + 1;
    const int CAP   = ((E / NBUCK) * 3 / 2 + 255) & ~255;

    auto align256 = [](size_t v) { return (v + 255) & ~(size_t)255; };
    char*           p        = (char*)d_ws;
    float*          dis      = (float*)p;          p += align256((size_t)N * 4);
    int*            ptr      = (int*)p;            p += align256((size_t)(N + 1) * 4);
    int*            hist     = (int*)p;            p += align256((size_t)N * 4);
    int*            partials = (int*)p;            p += align256((size_t)NB * 4);
    int*            bcur     = (int*)p;            p += align256(256 * 4);
    int*            csr      = (int*)p;            p += align256(((size_t)E + 8 * (size_t)N) * 4);
    int2*           bbuf     = (int2*)p;           p += align256((size_t)NBUCK * CAP * 8);
    unsigned short* xwb      = (unsigned short*)p; p += align256((size_t)(N + 1) * 64 * 2);
    unsigned short* whi1     = (unsigned short*)p; p += align256(128 * 64 * 2);
    unsigned short* wlo1     = (unsigned short*)p; p += align256(128 * 64 * 2);
    unsigned short* whi2     = (unsigned short*)p; p += align256(64 * 64 * 2);
    unsigned short* wlo2     = (unsigned short*)p; p += align256(64 * 64 * 2);

    // h (post-relu, f32) scratch lives in d_out: dead until agg_l2 overwrites it.
    float* hs = out;

    hipMemsetAsync(bcur, 0, 256 * 4, stream);                       // within-slab cursors
    hipMemsetAsync(xwb + (size_t)N * 64, 0, 64 * 2, stream);        // zero pad-row N
    prep_wfrag<<<1, 256, 0, stream>>>(W1, W2, whi1, wlo1, whi2, wlo2);
    passA<<<(E + PASSA_EDGES - 1) / PASSA_EDGES, 256, 0, stream>>>(src, dst, bcur, bbuf, E, CAP, shift);
    hist_dis<<<NBUCK, 256, 0, stream>>>(bbuf, bcur, hist, N, CAP, shift);
    scan_partial<<<NB, 256, 0, stream>>>(hist, partials, dis, N);
    scan_offsets<<<1, 256, 0, stream>>>(partials, NB);
    scan_apply<<<NB, 256, 0, stream>>>(hist, partials, ptr, N);
    passB<<<NBUCK, 256, 0, stream>>>(bbuf, bcur, ptr, csr, N, CAP, shift);

    gemm_mfma<128><<<(N + 63) / 64, 256, 0, stream>>>(x, whi1, wlo1, dis, xwb, N);
    agg_l1<<<(N + 31) / 32, 256, 0, stream>>>(xwb, csr, ptr, dis, b1, hs, N);
    // gemm2: h2'(bf16, prescaled, reuses xwb rows<N; row N stays zero) = h @ W2
    gemm_mfma<64><<<(N + 63) / 64, 256, 0, stream>>>(hs, whi2, wlo2, dis, xwb, N);
    agg_l2<<<(N + 31) / 32, 256, 0, stream>>>(xwb, csr, ptr, dis, b2, out, N);
}

// Round 11
// 257.453 us; speedup vs baseline: 1.2730x; 1.0584x over previous
//
#include <hip/hip_runtime.h>
#include <cstdint>
#include <cstddef>

#define PASSA_EDGES 2048

typedef __attribute__((ext_vector_type(8))) short bf16x8;   // 8 bf16 = 4 VGPR (MFMA A/B frag)
typedef __attribute__((ext_vector_type(4))) float f32x4;    // MFMA C/D frag

// ---------------- bf16 helpers ----------------

__device__ __forceinline__ unsigned short f2bf(float f) {  // RNE
    unsigned int u = __float_as_uint(f);
    u += 0x7FFFu + ((u >> 16) & 1u);
    return (unsigned short)(u >> 16);
}
__device__ __forceinline__ float bf2f(unsigned short h) {
    return __uint_as_float((unsigned int)h << 16);
}

// acc[8] += 8 bf16 (packed in uint4)  -- weight-free gather accumulate
__device__ __forceinline__ void bf8_acc(uint4 u, float* acc) {
    acc[0] += __uint_as_float(u.x << 16);
    acc[1] += __uint_as_float(u.x & 0xFFFF0000u);
    acc[2] += __uint_as_float(u.y << 16);
    acc[3] += __uint_as_float(u.y & 0xFFFF0000u);
    acc[4] += __uint_as_float(u.z << 16);
    acc[5] += __uint_as_float(u.z & 0xFFFF0000u);
    acc[6] += __uint_as_float(u.w << 16);
    acc[7] += __uint_as_float(u.w & 0xFFFF0000u);
}
__device__ __forceinline__ void bf8_unpack(uint4 u, float* v) {
    v[0] = __uint_as_float(u.x << 16);
    v[1] = __uint_as_float(u.x & 0xFFFF0000u);
    v[2] = __uint_as_float(u.y << 16);
    v[3] = __uint_as_float(u.y & 0xFFFF0000u);
    v[4] = __uint_as_float(u.z << 16);
    v[5] = __uint_as_float(u.z & 0xFFFF0000u);
    v[6] = __uint_as_float(u.w << 16);
    v[7] = __uint_as_float(u.w & 0xFFFF0000u);
}

// ---------------- pass A v5: bins image + FLAT coalesced writeout ------------------
// R11: R10's direct scatter issued 64 scattered 8B stores per wave-instr (each lane
// a different bucket cursor) -> 3x write amplification, 54us, and LOWER occupancy
// versions were faster (R8) -- transaction-rate-bound, not occupancy-bound.
// Fix: local counting sort into a 16KB LDS bins image (bucket-ordered), then a
// FLAT writeout: thread i recomputes b = bins[i].y>>shift and writes
// bbuf[gbase[b] + (i - off[b])]. Zero lane waste (vs R5/R6's per-bucket strided
// loops) and consecutive i in a bucket run -> consecutive global addresses:
// ~8 full-line segments per wave-instr instead of 64 scattered 8B stores.

__global__ __launch_bounds__(256) void passA(const int* __restrict__ src,
                                             const int* __restrict__ dst,
                                             int* __restrict__ bcur,
                                             int2* __restrict__ bbuf, int E,
                                             int CAP, int shift) {
    __shared__ int2 bins[PASSA_EDGES];
    __shared__ int  cnt[256], off[256], cur[256], gbase[256];
    const int t  = threadIdx.x;
    const int e0 = blockIdx.x * PASSA_EDGES;
    const int n  = min(PASSA_EDGES, E - e0);

    cnt[t] = 0;
    __syncthreads();
    for (int i = t; i < n; i += 256) atomicAdd(&cnt[dst[e0 + i] >> shift], 1);
    __syncthreads();

    // 256-wide exclusive scan (Hillis-Steele)
    const int v = cnt[t];
    off[t] = v;
    __syncthreads();
    for (int o = 1; o < 256; o <<= 1) {
        int u = (t >= o) ? off[t - o] : 0;
        __syncthreads();
        off[t] += u;
        __syncthreads();
    }
    const int excl = off[t] - v;
    off[t] = excl;                    // own-slot rewrite, no race
    cur[t] = excl;
    if (v > 0) gbase[t] = t * CAP + atomicAdd(&bcur[t], v);
    __syncthreads();

    // local scatter: bins becomes bucket-ordered
    for (int i = t; i < n; i += 256) {
        const int d = dst[e0 + i];
        const int s = src[e0 + i];
        const int p = atomicAdd(&cur[d >> shift], 1);
        bins[p] = make_int2(s, d);
    }
    __syncthreads();

    // flat writeout: every lane active, bucket-run-contiguous destinations
    for (int i = t; i < n; i += 256) {
        const int2 pr = bins[i];
        const int  b  = pr.y >> shift;
        const int  q  = gbase[b] + (i - off[b]);
        if (q < (b + 1) * CAP) bbuf[q] = pr;   // slab-overflow guard
    }
}

// ---------------- per-bucket histogram: TRUE degree (padding applied in scan) ------

__global__ __launch_bounds__(256) void hist_dis(const int2* __restrict__ bbuf,
                                                const int* __restrict__ bcur,
                                                int* __restrict__ hist,
                                                int N, int CAP, int shift) {
    __shared__ int cnt[1024];
    const int b     = blockIdx.x;
    const int node0 = b << shift;
    const int nn    = min(1 << shift, N - node0);
    for (int j = threadIdx.x; j < nn; j += 256) cnt[j] = 0;
    __syncthreads();
    const int start = b * CAP;
    const int end   = min(b * CAP + bcur[b], (b + 1) * CAP);
    for (int e = start + threadIdx.x; e < end; e += 256)
        atomicAdd(&cnt[bbuf[e].y - node0], 1);
    __syncthreads();
    for (int j = threadIdx.x; j < nn; j += 256) hist[node0 + j] = cnt[j];
}

// ---------------- 3-phase exclusive scan of 8-PADDED degrees; dis folded in --------

__global__ __launch_bounds__(256) void scan_partial(const int* __restrict__ hist,
                                                    int* __restrict__ partials,
                                                    float* __restrict__ dis, int N) {
    __shared__ int red[256];
    const int t    = threadIdx.x;
    const int base = blockIdx.x * 1024 + t * 4;
    int s = 0;
    if (base + 3 < N) {
        int4 v = *(const int4*)&hist[base];
        s = ((v.x + 7) & ~7) + ((v.y + 7) & ~7) + ((v.z + 7) & ~7) + ((v.w + 7) & ~7);
        dis[base]     = rsqrtf((float)(v.x + 1));  // +1 self loop
        dis[base + 1] = rsqrtf((float)(v.y + 1));
        dis[base + 2] = rsqrtf((float)(v.z + 1));
        dis[base + 3] = rsqrtf((float)(v.w + 1));
    } else {
        for (int i = 0; i < 4; i++)
            if (base + i < N) {
                int c = hist[base + i];
                s += (c + 7) & ~7;
                dis[base + i] = rsqrtf((float)(c + 1));
            }
    }
    red[t] = s;
    __syncthreads();
    for (int off = 128; off; off >>= 1) {
        if (t < off) red[t] += red[t + off];
        __syncthreads();
    }
    if (t == 0) partials[blockIdx.x] = red[0];
}

__global__ __launch_bounds__(256) void scan_offsets(int* __restrict__ partials, int NB) {
    __shared__ int tmp[256];
    const int t = threadIdx.x;
    int v = (t < NB) ? partials[t] : 0;
    tmp[t] = v;
    __syncthreads();
    for (int off = 1; off < 256; off <<= 1) {
        int u = (t >= off) ? tmp[t - off] : 0;
        __syncthreads();
        tmp[t] += u;
        __syncthreads();
    }
    if (t < NB) partials[t] = tmp[t] - v;
}

__global__ __launch_bounds__(256) void scan_apply(const int* __restrict__ hist,
                                                  const int* __restrict__ partials,
                                                  int* __restrict__ ptr, int N) {
    __shared__ int tsum[256];
    const int t    = threadIdx.x;
    const int base = blockIdx.x * 1024 + t * 4;
    int v[4];
    int s = 0;
    for (int i = 0; i < 4; i++) {
        int c = (base + i < N) ? hist[base + i] : 0;
        v[i]  = (c + 7) & ~7;
        s += v[i];
    }
    tsum[t] = s;
    __syncthreads();
    for (int off = 1; off < 256; off <<= 1) {
        int u = (t >= off) ? tsum[t - off] : 0;
        __syncthreads();
        tsum[t] += u;
        __syncthreads();
    }
    int run = partials[blockIdx.x] + tsum[t] - s;
    for (int i = 0; i < 4; i++) {
        if (base + i < N) {
            ptr[base + i] = run;
            run += v[i];
        }
    }
    if (base <= N - 1 && N - 1 < base + 4) ptr[N] = run;  // total = padded E
}

// ---------------- pass B: weight-free scatter -> int csr + fused pad fill ----------
// csr entries are src indices ONLY (4 B/edge; dis[src] folded into the GEMM row
// prescale). Pad slots (<=7/row) point at zero-row N. Direct writes land in the
// bucket's contiguous window -> no amplification.

__global__ __launch_bounds__(256) void passB(const int2* __restrict__ bbuf,
                                             const int* __restrict__ bcur,
                                             const int* __restrict__ ptr,
                                             int* __restrict__ csr,
                                             int N, int CAP, int shift) {
    __shared__ int lcur[1024];
    const int b     = blockIdx.x;
    const int node0 = b << shift;
    const int nn    = min(1 << shift, N - node0);
    for (int j = threadIdx.x; j < nn; j += 256) lcur[j] = ptr[node0 + j];
    __syncthreads();

    const int start = b * CAP;
    const int end   = min(b * CAP + bcur[b], (b + 1) * CAP);
    for (int e = start + threadIdx.x; e < end; e += 256) {
        const int2 pr = bbuf[e];
        const int  p  = atomicAdd(&lcur[pr.y - node0], 1);
        csr[p] = pr.x;
    }
    __syncthreads();

    for (int j = threadIdx.x; j < nn; j += 256) {
        const int t1 = ptr[node0 + j + 1];
        for (int p = lcur[j]; p < t1; ++p) csr[p] = N;   // zero-row pad
    }
}

// ---------------- W fragment prep: fp32 W -> fragment-ordered bf16 hi/lo ----------
// B-frag layout for mfma_f32_16x16x32_bf16: lane&15 = out-col n, lane>>4 = k-octet,
// 8 contiguous k per lane. Stored so lane l of frag-block (kstep*4+nt) reads its
// 16 B contiguously at [(kstep*4+nt)*512 + l*8]. hi = RNE(w); lo = RNE(w - hi):
// Xhi*Whi + Xlo*Whi + Xhi*Wlo reproduces fp32 to ~2^-17 (lo*lo dropped).

__global__ __launch_bounds__(256) void prep_wfrag(const float* __restrict__ W1,
                                                  const float* __restrict__ W2,
                                                  unsigned short* __restrict__ whi1,
                                                  unsigned short* __restrict__ wlo1,
                                                  unsigned short* __restrict__ whi2,
                                                  unsigned short* __restrict__ wlo2) {
    for (int e = threadIdx.x; e < 128 * 64; e += 256) {
        const int blk = e >> 9, l = (e >> 3) & 63, j = e & 7;
        const int k = (blk >> 2) * 32 + (l >> 4) * 8 + j;
        const int n = (blk & 3) * 16 + (l & 15);
        const float v = W1[k * 64 + n];
        const unsigned short h = f2bf(v);
        whi1[e] = h;
        wlo1[e] = f2bf(v - bf2f(h));
    }
    for (int e = threadIdx.x; e < 64 * 64; e += 256) {
        const int blk = e >> 9, l = (e >> 3) & 63, j = e & 7;
        const int k = (blk >> 2) * 32 + (l >> 4) * 8 + j;
        const int n = (blk & 3) * 16 + (l & 15);
        const float v = W2[k * 64 + n];
        const unsigned short h = f2bf(v);
        whi2[e] = h;
        wlo2[e] = f2bf(v - bf2f(h));
    }
}

// ---------------- MFMA GEMM: Yb[N x 64](bf16) = (X[N x K](f32) @ W) * dis[row] -----
// dis[row] prescale in the epilogue (f32 multiply before the bf16 round; enables
// the weight-free int csr). 64-row tile, 4 waves; X staged fp32 in padded LDS;
// A split bf16 hi/lo in-reg; B-frags coalesced from prep arrays; 3 MFMA per
// (kstep,ntile) = split-fp32. C/D: col = lane&15, row = (lane>>4)*4 + reg.

template <int K>
__global__ __launch_bounds__(256) void gemm_mfma(const float* __restrict__ X,
                                                 const unsigned short* __restrict__ whi,
                                                 const unsigned short* __restrict__ wlo,
                                                 const float* __restrict__ dis,
                                                 unsigned short* __restrict__ Yb, int N) {
    constexpr int LDX = K + 4;
    __shared__ float xs[64 * LDX];
    const int tid  = threadIdx.x;
    const int row0 = blockIdx.x * 64;

#pragma unroll
    for (int i = 0; i < (64 * K) / 1024; ++i) {
        const int fidx = i * 1024 + tid * 4;
        const int r = fidx / K, c = fidx % K;
        const float4 v = *(const float4*)(X + (size_t)min(row0 + r, N - 1) * K + c);
        *(float4*)&xs[r * LDX + c] = v;
    }
    __syncthreads();

    const int w = tid >> 6, l = tid & 63;
    const int m = l & 15, kg = l >> 4;

    f32x4 acc[4] = {};
    const float* xrow = &xs[(w * 16 + m) * LDX];

#pragma unroll
    for (int s = 0; s < K / 32; ++s) {
        const float4 a0 = *(const float4*)(xrow + s * 32 + kg * 8);
        const float4 a1 = *(const float4*)(xrow + s * 32 + kg * 8 + 4);
        const float av[8] = {a0.x, a0.y, a0.z, a0.w, a1.x, a1.y, a1.z, a1.w};
        bf16x8 ahi, alo;
#pragma unroll
        for (int j = 0; j < 8; ++j) {
            const unsigned short h = f2bf(av[j]);
            ahi[j] = (short)h;
            alo[j] = (short)f2bf(av[j] - bf2f(h));
        }
#pragma unroll
        for (int nt = 0; nt < 4; ++nt) {
            const bf16x8 bh = *(const bf16x8*)&whi[(s * 4 + nt) * 512 + l * 8];
            const bf16x8 bl = *(const bf16x8*)&wlo[(s * 4 + nt) * 512 + l * 8];
            acc[nt] = __builtin_amdgcn_mfma_f32_16x16x32_bf16(ahi, bh, acc[nt], 0, 0, 0);
            acc[nt] = __builtin_amdgcn_mfma_f32_16x16x32_bf16(alo, bh, acc[nt], 0, 0, 0);
            acc[nt] = __builtin_amdgcn_mfma_f32_16x16x32_bf16(ahi, bl, acc[nt], 0, 0, 0);
        }
    }

    float dv[4];
#pragma unroll
    for (int r = 0; r < 4; ++r)
        dv[r] = dis[min(row0 + w * 16 + kg * 4 + r, N - 1)];

#pragma unroll
    for (int nt = 0; nt < 4; ++nt)
#pragma unroll
        for (int r = 0; r < 4; ++r) {
            const int row = row0 + w * 16 + kg * 4 + r;
            if (row < N) Yb[(size_t)row * 64 + nt * 16 + m] = f2bf(acc[nt][r] * dv[r]);
        }
}

// ---------------- weight-free oct-row gather: 8 rows/wave, group-per-row -----------
// Slabs 8-padded; each lane reads its group's 8 src indices as 2 x int4 (32 B,
// broadcast across the 8 group lanes) then 8 independent prescaled-B row loads.
// Pad entries index zero-row N (contribute 0). Next chunk prefetched one iteration
// ahead; groups exit independently.

__device__ __forceinline__ void gather8i(const unsigned short* __restrict__ B,
                                         const int* __restrict__ csr,
                                         int s0, int iters, int co, float* acc) {
    const int4* cs = (const int4*)(csr + s0);   // 32B-aligned (s0 % 8 == 0)
    int4 c0 = make_int4(0, 0, 0, 0), c1 = c0;
    if (iters > 0) { c0 = cs[0]; c1 = cs[1]; }
    for (int it = 0; it < iters; ++it) {
        const int nb = min(it + 1, iters - 1) * 2;   // prefetch next chunk (clamped)
        int4 n0 = cs[nb], n1 = cs[nb + 1];
        uint4 u0 = *(const uint4*)&B[(size_t)c0.x * 64 + co * 8];
        uint4 u1 = *(const uint4*)&B[(size_t)c0.y * 64 + co * 8];
        uint4 u2 = *(const uint4*)&B[(size_t)c0.z * 64 + co * 8];
        uint4 u3 = *(const uint4*)&B[(size_t)c0.w * 64 + co * 8];
        uint4 u4 = *(const uint4*)&B[(size_t)c1.x * 64 + co * 8];
        uint4 u5 = *(const uint4*)&B[(size_t)c1.y * 64 + co * 8];
        uint4 u6 = *(const uint4*)&B[(size_t)c1.z * 64 + co * 8];
        uint4 u7 = *(const uint4*)&B[(size_t)c1.w * 64 + co * 8];
        bf8_acc(u0, acc);
        bf8_acc(u1, acc);
        bf8_acc(u2, acc);
        bf8_acc(u3, acc);
        bf8_acc(u4, acc);
        bf8_acc(u5, acc);
        bf8_acc(u6, acc);
        bf8_acc(u7, acc);
        c0 = n0; c1 = n1;
    }
}

// ---------------- layer 1: gather prescaled B + relu -> f32 h (scratch = d_out) ----
// result = (sum B'[e] + B'[row]) * dis[row] + b1  (B' rows already carry dis[src])

__global__ __launch_bounds__(256) void agg_l1(const unsigned short* __restrict__ B,
                                              const int* __restrict__ csr,
                                              const int* __restrict__ ptr,
                                              const float* __restrict__ dis,
                                              const float* __restrict__ b1,
                                              float* __restrict__ hs, int N) {
    const int wid  = threadIdx.x >> 6;
    const int lane = threadIdx.x & 63;
    const int eg   = lane >> 3;
    const int co   = lane & 7;

    const int  row = blockIdx.x * 32 + wid * 8 + eg;   // group eg owns this row
    const bool hr  = (row < N);

    const int   s0 = hr ? ptr[row] : 0;
    const int   s1 = hr ? ptr[row + 1] : 0;
    const float di = hr ? dis[row] : 0.f;
    const int   iters = (s1 - s0) >> 3;   // slabs are 8-padded

    float acc[8] = {};
    gather8i(B, csr, s0, iters, co, acc);

    if (!hr) return;

    uint4 us = *(const uint4*)&B[(size_t)row * 64 + co * 8];
    float bs[8];
    bf8_unpack(us, bs);
    float bb[8];
    *(float4*)&bb[0] = *(const float4*)&b1[co * 8];
    *(float4*)&bb[4] = *(const float4*)&b1[co * 8 + 4];

    float h[8];
#pragma unroll
    for (int i = 0; i < 8; i++)
        h[i] = fmaxf((acc[i] + bs[i]) * di + bb[i], 0.f);

    *(float4*)&hs[(size_t)row * 64 + co * 8]     = make_float4(h[0], h[1], h[2], h[3]);
    *(float4*)&hs[(size_t)row * 64 + co * 8 + 4] = make_float4(h[4], h[5], h[6], h[7]);
}

// ---------------- layer 2: gather prescaled h2 + bias + log_softmax -> fp32 out ----

__global__ __launch_bounds__(256) void agg_l2(const unsigned short* __restrict__ B,
                                              const int* __restrict__ csr,
                                              const int* __restrict__ ptr,
                                              const float* __restrict__ dis,
                                              const float* __restrict__ b2,
                                              float* __restrict__ out, int N) {
    const int wid  = threadIdx.x >> 6;
    const int lane = threadIdx.x & 63;
    const int eg   = lane >> 3;
    const int co   = lane & 7;

    const int  row = blockIdx.x * 32 + wid * 8 + eg;
    const bool hr  = (row < N);

    const int   s0 = hr ? ptr[row] : 0;
    const int   s1 = hr ? ptr[row + 1] : 0;
    const float di = hr ? dis[row] : 0.f;
    const int   iters = (s1 - s0) >> 3;

    float acc[8] = {};
    gather8i(B, csr, s0, iters, co, acc);

    if (!hr) return;

    uint4 us = *(const uint4*)&B[(size_t)row * 64 + co * 8];
    float bs[8];
    bf8_unpack(us, bs);
    float bb[8];
    *(float4*)&bb[0] = *(const float4*)&b2[co * 8];
    *(float4*)&bb[4] = *(const float4*)&b2[co * 8 + 4];

    float v[8];
#pragma unroll
    for (int i = 0; i < 8; i++) v[i] = (acc[i] + bs[i]) * di + bb[i];

    float m = v[0];
#pragma unroll
    for (int i = 1; i < 8; i++) m = fmaxf(m, v[i]);
#pragma unroll
    for (int off = 1; off <= 4; off <<= 1) m = fmaxf(m, __shfl_xor(m, off));
    float s = 0.f;
#pragma unroll
    for (int i = 0; i < 8; i++) s += __expf(v[i] - m);
#pragma unroll
    for (int off = 1; off <= 4; off <<= 1) s += __shfl_xor(s, off);
    float lse = m + __logf(s);

    float4 oa = make_float4(v[0] - lse, v[1] - lse, v[2] - lse, v[3] - lse);
    float4 ob = make_float4(v[4] - lse, v[5] - lse, v[6] - lse, v[7] - lse);
    *(float4*)&out[(size_t)row * 64 + co * 8]     = oa;
    *(float4*)&out[(size_t)row * 64 + co * 8 + 4] = ob;
}

// ---------------- launch ----------------

extern "C" void kernel_launch(void* const* d_in, const int* in_sizes, int n_in,
                              void* d_out, int out_size, void* d_ws, size_t ws_size,
                              hipStream_t stream) {
    const float* x   = (const float*)d_in[0];
    const int*   ei  = (const int*)d_in[1];
    const float* W1  = (const float*)d_in[2];
    const float* b1  = (const float*)d_in[3];
    const float* W2  = (const float*)d_in[4];
    const float* b2  = (const float*)d_in[5];
    float*       out = (float*)d_out;

    const int  N   = in_sizes[0] / 128;
    const int  E   = in_sizes[1] / 2;
    const int* src = ei;
    const int* dst = ei + E;
    const int  NB  = (N + 1023) / 1024;

    int shift = 9;
    while (((N - 1) >> shift) >= 256) shift++;
    const int NBUCK = ((N - 1) >> shift) + 1;
    const int CAP   = ((E / NBUCK) * 3 / 2 + 255) & ~255;

    auto align256 = [](size_t v) { return (v + 255) & ~(size_t)255; };
    char*           p        = (char*)d_ws;
    float*          dis      = (float*)p;          p += align256((size_t)N * 4);
    int*            ptr      = (int*)p;            p += align256((size_t)(N + 1) * 4);
    int*            hist     = (int*)p;            p += align256((size_t)N * 4);
    int*            partials = (int*)p;            p += align256((size_t)NB * 4);
    int*            bcur     = (int*)p;            p += align256(256 * 4);
    int*            csr      = (int*)p;            p += align256(((size_t)E + 8 * (size_t)N) * 4);
    int2*           bbuf     = (int2*)p;           p += align256((size_t)NBUCK * CAP * 8);
    unsigned short* xwb      = (unsigned short*)p; p += align256((size_t)(N + 1) * 64 * 2);
    unsigned short* whi1     = (unsigned short*)p; p += align256(128 * 64 * 2);
    unsigned short* wlo1     = (unsigned short*)p; p += align256(128 * 64 * 2);
    unsigned short* whi2     = (unsigned short*)p; p += align256(64 * 64 * 2);
    unsigned short* wlo2     = (unsigned short*)p; p += align256(64 * 64 * 2);

    // h (post-relu, f32) scratch lives in d_out: dead until agg_l2 overwrites it.
    float* hs = out;

    hipMemsetAsync(bcur, 0, 256 * 4, stream);                       // within-slab cursors
    hipMemsetAsync(xwb + (size_t)N * 64, 0, 64 * 2, stream);        // zero pad-row N
    prep_wfrag<<<1, 256, 0, stream>>>(W1, W2, whi1, wlo1, whi2, wlo2);
    passA<<<(E + PASSA_EDGES - 1) / PASSA_EDGES, 256, 0, stream>>>(src, dst, bcur, bbuf, E, CAP, shift);
    hist_dis<<<NBUCK, 256, 0, stream>>>(bbuf, bcur, hist, N, CAP, shift);
    scan_partial<<<NB, 256, 0, stream>>>(hist, partials, dis, N);
    scan_offsets<<<1, 256, 0, stream>>>(partials, NB);
    scan_apply<<<NB, 256, 0, stream>>>(hist, partials, ptr, N);
    passB<<<NBUCK, 256, 0, stream>>>(bbuf, bcur, ptr, csr, N, CAP, shift);

    gemm_mfma<128><<<(N + 63) / 64, 256, 0, stream>>>(x, whi1, wlo1, dis, xwb, N);
    agg_l1<<<(N + 31) / 32, 256, 0, stream>>>(xwb, csr, ptr, dis, b1, hs, N);
    // gemm2: h2'(bf16, prescaled, reuses xwb rows<N; row N stays zero) = h @ W2
    gemm_mfma<64><<<(N + 63) / 64, 256, 0, stream>>>(hs, whi2, wlo2, dis, xwb, N);
    agg_l2<<<(N + 31) / 32, 256, 0, stream>>>(xwb, csr, ptr, dis, b2, out, N);
}

// Round 12
// 250.734 us; speedup vs baseline: 1.3071x; 1.0268x over previous
//
#include <hip/hip_runtime.h>
#include <cstdint>
#include <cstddef>

#define PASSA_EDGES 2048

typedef __attribute__((ext_vector_type(8))) short bf16x8;   // 8 bf16 = 4 VGPR (MFMA A/B frag)
typedef __attribute__((ext_vector_type(4))) float f32x4;    // MFMA C/D frag

// ---------------- bf16 helpers ----------------

__device__ __forceinline__ unsigned short f2bf(float f) {  // RNE
    unsigned int u = __float_as_uint(f);
    u += 0x7FFFu + ((u >> 16) & 1u);
    return (unsigned short)(u >> 16);
}
__device__ __forceinline__ float bf2f(unsigned short h) {
    return __uint_as_float((unsigned int)h << 16);
}

// acc[8] += 8 bf16 (packed in uint4)  -- weight-free gather accumulate
__device__ __forceinline__ void bf8_acc(uint4 u, float* acc) {
    acc[0] += __uint_as_float(u.x << 16);
    acc[1] += __uint_as_float(u.x & 0xFFFF0000u);
    acc[2] += __uint_as_float(u.y << 16);
    acc[3] += __uint_as_float(u.y & 0xFFFF0000u);
    acc[4] += __uint_as_float(u.z << 16);
    acc[5] += __uint_as_float(u.z & 0xFFFF0000u);
    acc[6] += __uint_as_float(u.w << 16);
    acc[7] += __uint_as_float(u.w & 0xFFFF0000u);
}
__device__ __forceinline__ void bf8_unpack(uint4 u, float* v) {
    v[0] = __uint_as_float(u.x << 16);
    v[1] = __uint_as_float(u.x & 0xFFFF0000u);
    v[2] = __uint_as_float(u.y << 16);
    v[3] = __uint_as_float(u.y & 0xFFFF0000u);
    v[4] = __uint_as_float(u.z << 16);
    v[5] = __uint_as_float(u.z & 0xFFFF0000u);
    v[6] = __uint_as_float(u.w << 16);
    v[7] = __uint_as_float(u.w & 0xFFFF0000u);
}

// ---------------- pass A: bins image + FLAT coalesced writeout (R11, 257us-best) ---
// Local counting sort into a 16KB LDS bins image (bucket-ordered), then a FLAT
// writeout: thread i recomputes b = bins[i].y>>shift and writes
// bbuf[gbase[b] + (i - off[b])]. Zero lane waste; consecutive i in a bucket run ->
// consecutive global addresses (~8 full-line segments per wave-instr, no
// write amplification -- R10's direct scatter was 3x-amplified at 54us).

__global__ __launch_bounds__(256) void passA(const int* __restrict__ src,
                                             const int* __restrict__ dst,
                                             int* __restrict__ bcur,
                                             int2* __restrict__ bbuf, int E,
                                             int CAP, int shift) {
    __shared__ int2 bins[PASSA_EDGES];
    __shared__ int  cnt[256], off[256], cur[256], gbase[256];
    const int t  = threadIdx.x;
    const int e0 = blockIdx.x * PASSA_EDGES;
    const int n  = min(PASSA_EDGES, E - e0);

    cnt[t] = 0;
    __syncthreads();
    for (int i = t; i < n; i += 256) atomicAdd(&cnt[dst[e0 + i] >> shift], 1);
    __syncthreads();

    // 256-wide exclusive scan (Hillis-Steele)
    const int v = cnt[t];
    off[t] = v;
    __syncthreads();
    for (int o = 1; o < 256; o <<= 1) {
        int u = (t >= o) ? off[t - o] : 0;
        __syncthreads();
        off[t] += u;
        __syncthreads();
    }
    const int excl = off[t] - v;
    off[t] = excl;                    // own-slot rewrite, no race
    cur[t] = excl;
    if (v > 0) gbase[t] = t * CAP + atomicAdd(&bcur[t], v);
    __syncthreads();

    // local scatter: bins becomes bucket-ordered
    for (int i = t; i < n; i += 256) {
        const int d = dst[e0 + i];
        const int s = src[e0 + i];
        const int p = atomicAdd(&cur[d >> shift], 1);
        bins[p] = make_int2(s, d);
    }
    __syncthreads();

    // flat writeout: every lane active, bucket-run-contiguous destinations
    for (int i = t; i < n; i += 256) {
        const int2 pr = bins[i];
        const int  b  = pr.y >> shift;
        const int  q  = gbase[b] + (i - off[b]);
        if (q < (b + 1) * CAP) bbuf[q] = pr;   // slab-overflow guard
    }
}

// ---------------- build_csr: fused hist + LOCAL scan + scatter + pad + dis ---------
// R12: the global 3-phase scan existed only to make csr globally contiguous, but
// agg only needs (row_start, iters) pointing ANYWHERE. Each bucket gets a fixed
// csr window of CAPC ints (CAPC >= CAP + 7*nodes covers worst-case padding), so
// everything becomes bucket-local and ONE kernel replaces hist_dis + scan_partial
// + scan_offsets + scan_apply + passB (deletes a 19MB bbuf re-read, 1.6M LDS
// atomics, 4 launch gaps). rowptr[node] = {csr start, iters=pdeg>>3}; dis folded.
// All global writes land dense in the bucket window (R7/R9/R10: random scattered
// stores cost a full 64B line each -- never again).

__global__ __launch_bounds__(256) void build_csr(const int2* __restrict__ bbuf,
                                                 const int* __restrict__ bcur,
                                                 int2* __restrict__ rowptr,
                                                 float* __restrict__ dis,
                                                 int* __restrict__ csr,
                                                 int N, int CAP, int CAPC, int shift) {
    __shared__ int cnt[1024];
    __shared__ int lcur[1024];
    __shared__ int psum[256];
    const int t     = threadIdx.x;
    const int b     = blockIdx.x;
    const int node0 = b << shift;
    const int nn    = min(1 << shift, N - node0);

    for (int j = t; j < nn; j += 256) cnt[j] = 0;
    __syncthreads();

    const int start = b * CAP;
    const int end   = min(b * CAP + bcur[b], (b + 1) * CAP);
    for (int e = start + t; e < end; e += 256)
        atomicAdd(&cnt[bbuf[e].y - node0], 1);
    __syncthreads();

    // local exclusive scan of 8-padded degrees (4 nodes/thread + 256-wide HS)
    int v[4];
    int s = 0;
#pragma unroll
    for (int i = 0; i < 4; i++) {
        const int j = t * 4 + i;
        v[i] = (j < nn) ? ((cnt[j] + 7) & ~7) : 0;
        s += v[i];
    }
    psum[t] = s;
    __syncthreads();
    for (int o = 1; o < 256; o <<= 1) {
        int u = (t >= o) ? psum[t - o] : 0;
        __syncthreads();
        psum[t] += u;
        __syncthreads();
    }
    int run = b * CAPC + psum[t] - s;
#pragma unroll
    for (int i = 0; i < 4; i++) {
        const int j = t * 4 + i;
        if (j < nn) {
            lcur[j] = run;
            rowptr[node0 + j] = make_int2(run, v[i] >> 3);
            dis[node0 + j]    = rsqrtf((float)(cnt[j] + 1));  // +1 self loop
            run += v[i];
        }
    }
    __syncthreads();

    // scatter into the bucket's dense csr window
    for (int e = start + t; e < end; e += 256) {
        const int2 pr = bbuf[e];
        const int  p  = atomicAdd(&lcur[pr.y - node0], 1);
        csr[p] = pr.x;
    }
    __syncthreads();

    // pad fill: lcur[j] = rowstart + true deg; fill to rowstart + pdeg with row N
    int base2 = b * CAPC + psum[t] - s;
#pragma unroll
    for (int i = 0; i < 4; i++) {
        const int j = t * 4 + i;
        if (j < nn) {
            const int rowend = base2 + v[i];
            for (int p = lcur[j]; p < rowend; ++p) csr[p] = N;  // zero-row pad
            base2 += v[i];
        }
    }
}

// ---------------- W fragment prep: fp32 W -> fragment-ordered bf16 hi/lo ----------
// B-frag layout for mfma_f32_16x16x32_bf16: lane&15 = out-col n, lane>>4 = k-octet,
// 8 contiguous k per lane. Stored so lane l of frag-block (kstep*4+nt) reads its
// 16 B contiguously at [(kstep*4+nt)*512 + l*8]. hi = RNE(w); lo = RNE(w - hi):
// Xhi*Whi + Xlo*Whi + Xhi*Wlo reproduces fp32 to ~2^-17 (lo*lo dropped).

__global__ __launch_bounds__(256) void prep_wfrag(const float* __restrict__ W1,
                                                  const float* __restrict__ W2,
                                                  unsigned short* __restrict__ whi1,
                                                  unsigned short* __restrict__ wlo1,
                                                  unsigned short* __restrict__ whi2,
                                                  unsigned short* __restrict__ wlo2) {
    for (int e = threadIdx.x; e < 128 * 64; e += 256) {
        const int blk = e >> 9, l = (e >> 3) & 63, j = e & 7;
        const int k = (blk >> 2) * 32 + (l >> 4) * 8 + j;
        const int n = (blk & 3) * 16 + (l & 15);
        const float v = W1[k * 64 + n];
        const unsigned short h = f2bf(v);
        whi1[e] = h;
        wlo1[e] = f2bf(v - bf2f(h));
    }
    for (int e = threadIdx.x; e < 64 * 64; e += 256) {
        const int blk = e >> 9, l = (e >> 3) & 63, j = e & 7;
        const int k = (blk >> 2) * 32 + (l >> 4) * 8 + j;
        const int n = (blk & 3) * 16 + (l & 15);
        const float v = W2[k * 64 + n];
        const unsigned short h = f2bf(v);
        whi2[e] = h;
        wlo2[e] = f2bf(v - bf2f(h));
    }
}

// ---------------- MFMA GEMM: Yb[N x 64](bf16) = (X[N x K](f32) @ W) * dis[row] -----
// dis[row] prescale in the epilogue (f32 multiply before the bf16 round; enables
// the weight-free int csr). 64-row tile, 4 waves; X staged fp32 in padded LDS;
// A split bf16 hi/lo in-reg; B-frags coalesced from prep arrays; 3 MFMA per
// (kstep,ntile) = split-fp32. C/D: col = lane&15, row = (lane>>4)*4 + reg.

template <int K>
__global__ __launch_bounds__(256) void gemm_mfma(const float* __restrict__ X,
                                                 const unsigned short* __restrict__ whi,
                                                 const unsigned short* __restrict__ wlo,
                                                 const float* __restrict__ dis,
                                                 unsigned short* __restrict__ Yb, int N) {
    constexpr int LDX = K + 4;
    __shared__ float xs[64 * LDX];
    const int tid  = threadIdx.x;
    const int row0 = blockIdx.x * 64;

#pragma unroll
    for (int i = 0; i < (64 * K) / 1024; ++i) {
        const int fidx = i * 1024 + tid * 4;
        const int r = fidx / K, c = fidx % K;
        const float4 v = *(const float4*)(X + (size_t)min(row0 + r, N - 1) * K + c);
        *(float4*)&xs[r * LDX + c] = v;
    }
    __syncthreads();

    const int w = tid >> 6, l = tid & 63;
    const int m = l & 15, kg = l >> 4;

    f32x4 acc[4] = {};
    const float* xrow = &xs[(w * 16 + m) * LDX];

#pragma unroll
    for (int s = 0; s < K / 32; ++s) {
        const float4 a0 = *(const float4*)(xrow + s * 32 + kg * 8);
        const float4 a1 = *(const float4*)(xrow + s * 32 + kg * 8 + 4);
        const float av[8] = {a0.x, a0.y, a0.z, a0.w, a1.x, a1.y, a1.z, a1.w};
        bf16x8 ahi, alo;
#pragma unroll
        for (int j = 0; j < 8; ++j) {
            const unsigned short h = f2bf(av[j]);
            ahi[j] = (short)h;
            alo[j] = (short)f2bf(av[j] - bf2f(h));
        }
#pragma unroll
        for (int nt = 0; nt < 4; ++nt) {
            const bf16x8 bh = *(const bf16x8*)&whi[(s * 4 + nt) * 512 + l * 8];
            const bf16x8 bl = *(const bf16x8*)&wlo[(s * 4 + nt) * 512 + l * 8];
            acc[nt] = __builtin_amdgcn_mfma_f32_16x16x32_bf16(ahi, bh, acc[nt], 0, 0, 0);
            acc[nt] = __builtin_amdgcn_mfma_f32_16x16x32_bf16(alo, bh, acc[nt], 0, 0, 0);
            acc[nt] = __builtin_amdgcn_mfma_f32_16x16x32_bf16(ahi, bl, acc[nt], 0, 0, 0);
        }
    }

    float dv[4];
#pragma unroll
    for (int r = 0; r < 4; ++r)
        dv[r] = dis[min(row0 + w * 16 + kg * 4 + r, N - 1)];

#pragma unroll
    for (int nt = 0; nt < 4; ++nt)
#pragma unroll
        for (int r = 0; r < 4; ++r) {
            const int row = row0 + w * 16 + kg * 4 + r;
            if (row < N) Yb[(size_t)row * 64 + nt * 16 + m] = f2bf(acc[nt][r] * dv[r]);
        }
}

// ---------------- weight-free oct-row gather: 8 rows/wave, group-per-row -----------
// Slabs 8-padded; each lane reads its group's 8 src indices as 2 x int4 (32 B,
// broadcast across the 8 group lanes) then 8 independent prescaled-B row loads.
// Pad entries index zero-row N (contribute 0). Next chunk prefetched one iteration
// ahead; groups exit independently. Fabric-throughput-bound (~6 TB/s aggregate
// random 128B rows); per-wave MLP is already ample (8KB pending/wave) -- unrolling
// is RF-budget break-even, not attempted.

__device__ __forceinline__ void gather8i(const unsigned short* __restrict__ B,
                                         const int* __restrict__ csr,
                                         int s0, int iters, int co, float* acc) {
    const int4* cs = (const int4*)(csr + s0);   // 32B-aligned (s0 % 8 == 0)
    int4 c0 = make_int4(0, 0, 0, 0), c1 = c0;
    if (iters > 0) { c0 = cs[0]; c1 = cs[1]; }
    for (int it = 0; it < iters; ++it) {
        const int nb = min(it + 1, iters - 1) * 2;   // prefetch next chunk (clamped)
        int4 n0 = cs[nb], n1 = cs[nb + 1];
        uint4 u0 = *(const uint4*)&B[(size_t)c0.x * 64 + co * 8];
        uint4 u1 = *(const uint4*)&B[(size_t)c0.y * 64 + co * 8];
        uint4 u2 = *(const uint4*)&B[(size_t)c0.z * 64 + co * 8];
        uint4 u3 = *(const uint4*)&B[(size_t)c0.w * 64 + co * 8];
        uint4 u4 = *(const uint4*)&B[(size_t)c1.x * 64 + co * 8];
        uint4 u5 = *(const uint4*)&B[(size_t)c1.y * 64 + co * 8];
        uint4 u6 = *(const uint4*)&B[(size_t)c1.z * 64 + co * 8];
        uint4 u7 = *(const uint4*)&B[(size_t)c1.w * 64 + co * 8];
        bf8_acc(u0, acc);
        bf8_acc(u1, acc);
        bf8_acc(u2, acc);
        bf8_acc(u3, acc);
        bf8_acc(u4, acc);
        bf8_acc(u5, acc);
        bf8_acc(u6, acc);
        bf8_acc(u7, acc);
        c0 = n0; c1 = n1;
    }
}

// ---------------- layer 1: gather prescaled B + relu -> f32 h (scratch = d_out) ----
// result = (sum B'[e] + B'[row]) * dis[row] + b1  (B' rows already carry dis[src])

__global__ __launch_bounds__(256) void agg_l1(const unsigned short* __restrict__ B,
                                              const int* __restrict__ csr,
                                              const int2* __restrict__ rowptr,
                                              const float* __restrict__ dis,
                                              const float* __restrict__ b1,
                                              float* __restrict__ hs, int N) {
    const int wid  = threadIdx.x >> 6;
    const int lane = threadIdx.x & 63;
    const int eg   = lane >> 3;
    const int co   = lane & 7;

    const int  row = blockIdx.x * 32 + wid * 8 + eg;   // group eg owns this row
    const bool hr  = (row < N);

    const int2  rp = hr ? rowptr[row] : make_int2(0, 0);
    const float di = hr ? dis[row] : 0.f;

    float acc[8] = {};
    gather8i(B, csr, rp.x, rp.y, co, acc);

    if (!hr) return;

    uint4 us = *(const uint4*)&B[(size_t)row * 64 + co * 8];
    float bs[8];
    bf8_unpack(us, bs);
    float bb[8];
    *(float4*)&bb[0] = *(const float4*)&b1[co * 8];
    *(float4*)&bb[4] = *(const float4*)&b1[co * 8 + 4];

    float h[8];
#pragma unroll
    for (int i = 0; i < 8; i++)
        h[i] = fmaxf((acc[i] + bs[i]) * di + bb[i], 0.f);

    *(float4*)&hs[(size_t)row * 64 + co * 8]     = make_float4(h[0], h[1], h[2], h[3]);
    *(float4*)&hs[(size_t)row * 64 + co * 8 + 4] = make_float4(h[4], h[5], h[6], h[7]);
}

// ---------------- layer 2: gather prescaled h2 + bias + log_softmax -> fp32 out ----

__global__ __launch_bounds__(256) void agg_l2(const unsigned short* __restrict__ B,
                                              const int* __restrict__ csr,
                                              const int2* __restrict__ rowptr,
                                              const float* __restrict__ dis,
                                              const float* __restrict__ b2,
                                              float* __restrict__ out, int N) {
    const int wid  = threadIdx.x >> 6;
    const int lane = threadIdx.x & 63;
    const int eg   = lane >> 3;
    const int co   = lane & 7;

    const int  row = blockIdx.x * 32 + wid * 8 + eg;
    const bool hr  = (row < N);

    const int2  rp = hr ? rowptr[row] : make_int2(0, 0);
    const float di = hr ? dis[row] : 0.f;

    float acc[8] = {};
    gather8i(B, csr, rp.x, rp.y, co, acc);

    if (!hr) return;

    uint4 us = *(const uint4*)&B[(size_t)row * 64 + co * 8];
    float bs[8];
    bf8_unpack(us, bs);
    float bb[8];
    *(float4*)&bb[0] = *(const float4*)&b2[co * 8];
    *(float4*)&bb[4] = *(const float4*)&b2[co * 8 + 4];

    float v[8];
#pragma unroll
    for (int i = 0; i < 8; i++) v[i] = (acc[i] + bs[i]) * di + bb[i];

    float m = v[0];
#pragma unroll
    for (int i = 1; i < 8; i++) m = fmaxf(m, v[i]);
#pragma unroll
    for (int off = 1; off <= 4; off <<= 1) m = fmaxf(m, __shfl_xor(m, off));
    float s = 0.f;
#pragma unroll
    for (int i = 0; i < 8; i++) s += __expf(v[i] - m);
#pragma unroll
    for (int off = 1; off <= 4; off <<= 1) s += __shfl_xor(s, off);
    float lse = m + __logf(s);

    float4 oa = make_float4(v[0] - lse, v[1] - lse, v[2] - lse, v[3] - lse);
    float4 ob = make_float4(v[4] - lse, v[5] - lse, v[6] - lse, v[7] - lse);
    *(float4*)&out[(size_t)row * 64 + co * 8]     = oa;
    *(float4*)&out[(size_t)row * 64 + co * 8 + 4] = ob;
}

// ---------------- launch ----------------

extern "C" void kernel_launch(void* const* d_in, const int* in_sizes, int n_in,
                              void* d_out, int out_size, void* d_ws, size_t ws_size,
                              hipStream_t stream) {
    const float* x   = (const float*)d_in[0];
    const int*   ei  = (const int*)d_in[1];
    const float* W1  = (const float*)d_in[2];
    const float* b1  = (const float*)d_in[3];
    const float* W2  = (const float*)d_in[4];
    const float* b2  = (const float*)d_in[5];
    float*       out = (float*)d_out;

    const int  N   = in_sizes[0] / 128;
    const int  E   = in_sizes[1] / 2;
    const int* src = ei;
    const int* dst = ei + E;

    int shift = 9;
    while (((N - 1) >> shift) >= 256) shift++;
    const int NBUCK = ((N - 1) >> shift) + 1;
    const int CAP   = ((E / NBUCK) * 3 / 2 + 255) & ~255;
    const int CAPC  = CAP + 8 * (1 << shift);   // edges + worst-case pad, per bucket

    auto align256 = [](size_t v) { return (v + 255) & ~(size_t)255; };
    char*           p        = (char*)d_ws;
    float*          dis      = (float*)p;          p += align256((size_t)N * 4);
    int2*           rowptr   = (int2*)p;           p += align256((size_t)N * 8);
    int*            bcur     = (int*)p;            p += align256(256 * 4);
    int*            csr      = (int*)p;            p += align256((size_t)NBUCK * CAPC * 4);
    int2*           bbuf     = (int2*)p;           p += align256((size_t)NBUCK * CAP * 8);
    unsigned short* xwb      = (unsigned short*)p; p += align256((size_t)(N + 1) * 64 * 2);
    unsigned short* whi1     = (unsigned short*)p; p += align256(128 * 64 * 2);
    unsigned short* wlo1     = (unsigned short*)p; p += align256(128 * 64 * 2);
    unsigned short* whi2     = (unsigned short*)p; p += align256(64 * 64 * 2);
    unsigned short* wlo2     = (unsigned short*)p; p += align256(64 * 64 * 2);

    // h (post-relu, f32) scratch lives in d_out: dead until agg_l2 overwrites it.
    float* hs = out;

    hipMemsetAsync(bcur, 0, 256 * 4, stream);                       // within-slab cursors
    hipMemsetAsync(xwb + (size_t)N * 64, 0, 64 * 2, stream);        // zero pad-row N
    prep_wfrag<<<1, 256, 0, stream>>>(W1, W2, whi1, wlo1, whi2, wlo2);
    passA<<<(E + PASSA_EDGES - 1) / PASSA_EDGES, 256, 0, stream>>>(src, dst, bcur, bbuf, E, CAP, shift);
    build_csr<<<NBUCK, 256, 0, stream>>>(bbuf, bcur, rowptr, dis, csr, N, CAP, CAPC, shift);

    gemm_mfma<128><<<(N + 63) / 64, 256, 0, stream>>>(x, whi1, wlo1, dis, xwb, N);
    agg_l1<<<(N + 31) / 32, 256, 0, stream>>>(xwb, csr, rowptr, dis, b1, hs, N);
    // gemm2: h2'(bf16, prescaled, reuses xwb rows<N; row N stays zero) = h @ W2
    gemm_mfma<64><<<(N + 63) / 64, 256, 0, stream>>>(hs, whi2, wlo2, dis, xwb, N);
    agg_l2<<<(N + 31) / 32, 256, 0, stream>>>(xwb, csr, rowptr, dis, b2, out, N);
}

// Round 13
// 236.587 us; speedup vs baseline: 1.3853x; 1.0598x over previous
//
#include <hip/hip_runtime.h>
#include <cstdint>
#include <cstddef>

#define PASSA_EDGES 2048

typedef __attribute__((ext_vector_type(8))) short bf16x8;   // 8 bf16 = 4 VGPR (MFMA A/B frag)
typedef __attribute__((ext_vector_type(4))) float f32x4;    // MFMA C/D frag

// ---------------- bf16 helpers ----------------

__device__ __forceinline__ unsigned short f2bf(float f) {  // RNE
    unsigned int u = __float_as_uint(f);
    u += 0x7FFFu + ((u >> 16) & 1u);
    return (unsigned short)(u >> 16);
}
__device__ __forceinline__ float bf2f(unsigned short h) {
    return __uint_as_float((unsigned int)h << 16);
}

// acc[8] += 8 bf16 (packed in uint4)  -- weight-free gather accumulate
__device__ __forceinline__ void bf8_acc(uint4 u, float* acc) {
    acc[0] += __uint_as_float(u.x << 16);
    acc[1] += __uint_as_float(u.x & 0xFFFF0000u);
    acc[2] += __uint_as_float(u.y << 16);
    acc[3] += __uint_as_float(u.y & 0xFFFF0000u);
    acc[4] += __uint_as_float(u.z << 16);
    acc[5] += __uint_as_float(u.z & 0xFFFF0000u);
    acc[6] += __uint_as_float(u.w << 16);
    acc[7] += __uint_as_float(u.w & 0xFFFF0000u);
}
__device__ __forceinline__ void bf8_unpack(uint4 u, float* v) {
    v[0] = __uint_as_float(u.x << 16);
    v[1] = __uint_as_float(u.x & 0xFFFF0000u);
    v[2] = __uint_as_float(u.y << 16);
    v[3] = __uint_as_float(u.y & 0xFFFF0000u);
    v[4] = __uint_as_float(u.z << 16);
    v[5] = __uint_as_float(u.z & 0xFFFF0000u);
    v[6] = __uint_as_float(u.w << 16);
    v[7] = __uint_as_float(u.w & 0xFFFF0000u);
}

// ---------------- pass A: bins image + FLAT coalesced writeout (R11, 257us-best) ---
// Local counting sort into a 16KB LDS bins image (bucket-ordered), then a FLAT
// writeout: thread i recomputes b = bins[i].y>>shift and writes
// bbuf[gbase[b] + (i - off[b])]. Zero lane waste; consecutive i in a bucket run ->
// consecutive global addresses (~8 full-line segments per wave-instr, no
// write amplification -- R10's direct scatter was 3x-amplified at 54us).

__global__ __launch_bounds__(256) void passA(const int* __restrict__ src,
                                             const int* __restrict__ dst,
                                             int* __restrict__ bcur,
                                             int2* __restrict__ bbuf, int E,
                                             int CAP, int shift) {
    __shared__ int2 bins[PASSA_EDGES];
    __shared__ int  cnt[256], off[256], cur[256], gbase[256];
    const int t  = threadIdx.x;
    const int e0 = blockIdx.x * PASSA_EDGES;
    const int n  = min(PASSA_EDGES, E - e0);

    cnt[t] = 0;
    __syncthreads();
    for (int i = t; i < n; i += 256) atomicAdd(&cnt[dst[e0 + i] >> shift], 1);
    __syncthreads();

    // 256-wide exclusive scan (Hillis-Steele)
    const int v = cnt[t];
    off[t] = v;
    __syncthreads();
    for (int o = 1; o < 256; o <<= 1) {
        int u = (t >= o) ? off[t - o] : 0;
        __syncthreads();
        off[t] += u;
        __syncthreads();
    }
    const int excl = off[t] - v;
    off[t] = excl;                    // own-slot rewrite, no race
    cur[t] = excl;
    if (v > 0) gbase[t] = t * CAP + atomicAdd(&bcur[t], v);
    __syncthreads();

    // local scatter: bins becomes bucket-ordered
    for (int i = t; i < n; i += 256) {
        const int d = dst[e0 + i];
        const int s = src[e0 + i];
        const int p = atomicAdd(&cur[d >> shift], 1);
        bins[p] = make_int2(s, d);
    }
    __syncthreads();

    // flat writeout: every lane active, bucket-run-contiguous destinations
    for (int i = t; i < n; i += 256) {
        const int2 pr = bins[i];
        const int  b  = pr.y >> shift;
        const int  q  = gbase[b] + (i - off[b]);
        if (q < (b + 1) * CAP) bbuf[q] = pr;   // slab-overflow guard
    }
}

// ---------------- build_csr: fused hist + LOCAL scan + scatter + pad + dis ---------
// Each bucket owns a fixed csr window of CAPC ints (>= CAP + 7*nodes worst-case
// padding); everything bucket-local: hist + local scan + scatter + pad fill + dis
// in ONE kernel. rowptr[node] = {csr start, iters=pdeg>>3}. All global writes land
// dense in the bucket window (R7/R9/R10: random scattered stores = 64B line each).

__global__ __launch_bounds__(256) void build_csr(const int2* __restrict__ bbuf,
                                                 const int* __restrict__ bcur,
                                                 int2* __restrict__ rowptr,
                                                 float* __restrict__ dis,
                                                 int* __restrict__ csr,
                                                 int N, int CAP, int CAPC, int shift) {
    __shared__ int cnt[1024];
    __shared__ int lcur[1024];
    __shared__ int psum[256];
    const int t     = threadIdx.x;
    const int b     = blockIdx.x;
    const int node0 = b << shift;
    const int nn    = min(1 << shift, N - node0);

    for (int j = t; j < nn; j += 256) cnt[j] = 0;
    __syncthreads();

    const int start = b * CAP;
    const int end   = min(b * CAP + bcur[b], (b + 1) * CAP);
    for (int e = start + t; e < end; e += 256)
        atomicAdd(&cnt[bbuf[e].y - node0], 1);
    __syncthreads();

    // local exclusive scan of 8-padded degrees (4 nodes/thread + 256-wide HS)
    int v[4];
    int s = 0;
#pragma unroll
    for (int i = 0; i < 4; i++) {
        const int j = t * 4 + i;
        v[i] = (j < nn) ? ((cnt[j] + 7) & ~7) : 0;
        s += v[i];
    }
    psum[t] = s;
    __syncthreads();
    for (int o = 1; o < 256; o <<= 1) {
        int u = (t >= o) ? psum[t - o] : 0;
        __syncthreads();
        psum[t] += u;
        __syncthreads();
    }
    int run = b * CAPC + psum[t] - s;
#pragma unroll
    for (int i = 0; i < 4; i++) {
        const int j = t * 4 + i;
        if (j < nn) {
            lcur[j] = run;
            rowptr[node0 + j] = make_int2(run, v[i] >> 3);
            dis[node0 + j]    = rsqrtf((float)(cnt[j] + 1));  // +1 self loop
            run += v[i];
        }
    }
    __syncthreads();

    // scatter into the bucket's dense csr window
    for (int e = start + t; e < end; e += 256) {
        const int2 pr = bbuf[e];
        const int  p  = atomicAdd(&lcur[pr.y - node0], 1);
        csr[p] = pr.x;
    }
    __syncthreads();

    // pad fill: lcur[j] = rowstart + true deg; fill to rowstart + pdeg with row N
    int base2 = b * CAPC + psum[t] - s;
#pragma unroll
    for (int i = 0; i < 4; i++) {
        const int j = t * 4 + i;
        if (j < nn) {
            const int rowend = base2 + v[i];
            for (int p = lcur[j]; p < rowend; ++p) csr[p] = N;  // zero-row pad
            base2 += v[i];
        }
    }
}

// ---------------- W fragment prep + init (fp32 W -> fragment-ordered bf16 hi/lo) ---
// B-frag layout for mfma_f32_16x16x32_bf16: lane&15 = out-col n, lane>>4 = k-octet,
// 8 contiguous k per lane. Stored so lane l of frag-block (kstep*4+nt) reads its
// 16 B contiguously at [(kstep*4+nt)*512 + l*8]. hi = RNE(w); lo = RNE(w - hi):
// Xhi*Whi + Xlo*Whi + Xhi*Wlo reproduces fp32 to ~2^-17 (lo*lo dropped).
// R13: also zeros bcur + the two pad rows (replaces 2 memset launches).

__global__ __launch_bounds__(256) void prep_wfrag(const float* __restrict__ W1,
                                                  const float* __restrict__ W2,
                                                  unsigned short* __restrict__ whi1,
                                                  unsigned short* __restrict__ wlo1,
                                                  unsigned short* __restrict__ whi2,
                                                  unsigned short* __restrict__ wlo2,
                                                  int* __restrict__ bcur,
                                                  unsigned short* __restrict__ xwb,
                                                  unsigned short* __restrict__ h2b,
                                                  int N) {
    bcur[threadIdx.x] = 0;
    if (threadIdx.x < 64) {
        xwb[(size_t)N * 64 + threadIdx.x] = 0;   // zero pad-row N (layer-1 table)
        h2b[(size_t)N * 64 + threadIdx.x] = 0;   // zero pad-row N (layer-2 table)
    }
    for (int e = threadIdx.x; e < 128 * 64; e += 256) {
        const int blk = e >> 9, l = (e >> 3) & 63, j = e & 7;
        const int k = (blk >> 2) * 32 + (l >> 4) * 8 + j;
        const int n = (blk & 3) * 16 + (l & 15);
        const float v = W1[k * 64 + n];
        const unsigned short h = f2bf(v);
        whi1[e] = h;
        wlo1[e] = f2bf(v - bf2f(h));
    }
    for (int e = threadIdx.x; e < 64 * 64; e += 256) {
        const int blk = e >> 9, l = (e >> 3) & 63, j = e & 7;
        const int k = (blk >> 2) * 32 + (l >> 4) * 8 + j;
        const int n = (blk & 3) * 16 + (l & 15);
        const float v = W2[k * 64 + n];
        const unsigned short h = f2bf(v);
        whi2[e] = h;
        wlo2[e] = f2bf(v - bf2f(h));
    }
}

// ---------------- MFMA GEMM: Yb[N x 64](bf16) = (X[N x K](f32) @ W) * dis[row] -----
// dis[row] prescale in the epilogue (f32 multiply before the bf16 round; enables
// the weight-free int csr). 64-row tile, 4 waves; X staged fp32 in padded LDS;
// A split bf16 hi/lo in-reg; B-frags coalesced from prep arrays; 3 MFMA per
// (kstep,ntile) = split-fp32. C/D: col = lane&15, row = (lane>>4)*4 + reg.

template <int K>
__global__ __launch_bounds__(256) void gemm_mfma(const float* __restrict__ X,
                                                 const unsigned short* __restrict__ whi,
                                                 const unsigned short* __restrict__ wlo,
                                                 const float* __restrict__ dis,
                                                 unsigned short* __restrict__ Yb, int N) {
    constexpr int LDX = K + 4;
    __shared__ float xs[64 * LDX];
    const int tid  = threadIdx.x;
    const int row0 = blockIdx.x * 64;

#pragma unroll
    for (int i = 0; i < (64 * K) / 1024; ++i) {
        const int fidx = i * 1024 + tid * 4;
        const int r = fidx / K, c = fidx % K;
        const float4 v = *(const float4*)(X + (size_t)min(row0 + r, N - 1) * K + c);
        *(float4*)&xs[r * LDX + c] = v;
    }
    __syncthreads();

    const int w = tid >> 6, l = tid & 63;
    const int m = l & 15, kg = l >> 4;

    f32x4 acc[4] = {};
    const float* xrow = &xs[(w * 16 + m) * LDX];

#pragma unroll
    for (int s = 0; s < K / 32; ++s) {
        const float4 a0 = *(const float4*)(xrow + s * 32 + kg * 8);
        const float4 a1 = *(const float4*)(xrow + s * 32 + kg * 8 + 4);
        const float av[8] = {a0.x, a0.y, a0.z, a0.w, a1.x, a1.y, a1.z, a1.w};
        bf16x8 ahi, alo;
#pragma unroll
        for (int j = 0; j < 8; ++j) {
            const unsigned short h = f2bf(av[j]);
            ahi[j] = (short)h;
            alo[j] = (short)f2bf(av[j] - bf2f(h));
        }
#pragma unroll
        for (int nt = 0; nt < 4; ++nt) {
            const bf16x8 bh = *(const bf16x8*)&whi[(s * 4 + nt) * 512 + l * 8];
            const bf16x8 bl = *(const bf16x8*)&wlo[(s * 4 + nt) * 512 + l * 8];
            acc[nt] = __builtin_amdgcn_mfma_f32_16x16x32_bf16(ahi, bh, acc[nt], 0, 0, 0);
            acc[nt] = __builtin_amdgcn_mfma_f32_16x16x32_bf16(alo, bh, acc[nt], 0, 0, 0);
            acc[nt] = __builtin_amdgcn_mfma_f32_16x16x32_bf16(ahi, bl, acc[nt], 0, 0, 0);
        }
    }

    float dv[4];
#pragma unroll
    for (int r = 0; r < 4; ++r)
        dv[r] = dis[min(row0 + w * 16 + kg * 4 + r, N - 1)];

#pragma unroll
    for (int nt = 0; nt < 4; ++nt)
#pragma unroll
        for (int r = 0; r < 4; ++r) {
            const int row = row0 + w * 16 + kg * 4 + r;
            if (row < N) Yb[(size_t)row * 64 + nt * 16 + m] = f2bf(acc[nt][r] * dv[r]);
        }
}

// ---------------- weight-free oct-row gather: 8 rows/wave, group-per-row -----------
// Slabs 8-padded; each lane reads its group's 8 src indices as 2 x int4 (32 B,
// broadcast across the 8 group lanes) then 8 independent prescaled-B row loads.
// Pad entries index zero-row N (contribute 0). Next chunk prefetched one iteration
// ahead; groups exit independently.

__device__ __forceinline__ void gather8i(const unsigned short* __restrict__ B,
                                         const int* __restrict__ csr,
                                         int s0, int iters, int co, float* acc) {
    const int4* cs = (const int4*)(csr + s0);   // 32B-aligned (s0 % 8 == 0)
    int4 c0 = make_int4(0, 0, 0, 0), c1 = c0;
    if (iters > 0) { c0 = cs[0]; c1 = cs[1]; }
    for (int it = 0; it < iters; ++it) {
        const int nb = min(it + 1, iters - 1) * 2;   // prefetch next chunk (clamped)
        int4 n0 = cs[nb], n1 = cs[nb + 1];
        uint4 u0 = *(const uint4*)&B[(size_t)c0.x * 64 + co * 8];
        uint4 u1 = *(const uint4*)&B[(size_t)c0.y * 64 + co * 8];
        uint4 u2 = *(const uint4*)&B[(size_t)c0.z * 64 + co * 8];
        uint4 u3 = *(const uint4*)&B[(size_t)c0.w * 64 + co * 8];
        uint4 u4 = *(const uint4*)&B[(size_t)c1.x * 64 + co * 8];
        uint4 u5 = *(const uint4*)&B[(size_t)c1.y * 64 + co * 8];
        uint4 u6 = *(const uint4*)&B[(size_t)c1.z * 64 + co * 8];
        uint4 u7 = *(const uint4*)&B[(size_t)c1.w * 64 + co * 8];
        bf8_acc(u0, acc);
        bf8_acc(u1, acc);
        bf8_acc(u2, acc);
        bf8_acc(u3, acc);
        bf8_acc(u4, acc);
        bf8_acc(u5, acc);
        bf8_acc(u6, acc);
        bf8_acc(u7, acc);
        c0 = n0; c1 = n1;
    }
}

// ---------------- layer 1 FUSED: gather + relu + in-block MFMA gemm2 -> h2b bf16 ---
// R13: h2[r] = h[r] @ W2 is ROW-WISE, so it fuses into agg_l1 legally (each block
// owns 32 complete rows). Phase 1: gather + self + bias + relu -> h staged in LDS
// (f32, exact -- bitwise-identical input to what gemm_mfma<64> read from hs).
// Phase 2: 8 output tiles (2 row-tiles x 4 ntiles) over 4 waves, same split-bf16
// 3-MFMA recipe + dis prescale as gemm_mfma. Deletes the hs 51MB HBM round trip
// and the gemm<64> launch. Output goes to h2b (NOT xwb: other blocks still gather
// xwb concurrently).

__global__ __launch_bounds__(256) void agg_l1f(const unsigned short* __restrict__ B,
                                               const int* __restrict__ csr,
                                               const int2* __restrict__ rowptr,
                                               const float* __restrict__ dis,
                                               const float* __restrict__ b1,
                                               const unsigned short* __restrict__ whi2,
                                               const unsigned short* __restrict__ wlo2,
                                               unsigned short* __restrict__ h2b, int N) {
    __shared__ float hsm[32][68];   // 32 rows x 64 ch, +4 pad (bank stride 4m -> 2-way, free)
    __shared__ float dsm[32];
    const int wid  = threadIdx.x >> 6;
    const int lane = threadIdx.x & 63;
    const int eg   = lane >> 3;
    const int co   = lane & 7;
    const int lrow = wid * 8 + eg;

    const int  row = blockIdx.x * 32 + lrow;   // group eg of wave wid owns this row
    const bool hr  = (row < N);

    const int2  rp = hr ? rowptr[row] : make_int2(0, 0);
    const float di = hr ? dis[row] : 0.f;

    float acc[8] = {};
    gather8i(B, csr, rp.x, rp.y, co, acc);

    float h[8] = {};
    if (hr) {
        uint4 us = *(const uint4*)&B[(size_t)row * 64 + co * 8];
        float bs[8];
        bf8_unpack(us, bs);
        float bb[8];
        *(float4*)&bb[0] = *(const float4*)&b1[co * 8];
        *(float4*)&bb[4] = *(const float4*)&b1[co * 8 + 4];
#pragma unroll
        for (int i = 0; i < 8; i++)
            h[i] = fmaxf((acc[i] + bs[i]) * di + bb[i], 0.f);
    }
    *(float4*)&hsm[lrow][co * 8]     = make_float4(h[0], h[1], h[2], h[3]);
    *(float4*)&hsm[lrow][co * 8 + 4] = make_float4(h[4], h[5], h[6], h[7]);
    if (co == 0) dsm[lrow] = di;
    __syncthreads();

    // ---- in-block gemm2: wave wid handles row-tile rt = wid&1, ntiles {wid>>1, (wid>>1)+2}
    const int m  = lane & 15, kg = lane >> 4;
    const int rt = wid & 1;
    const int n0t = wid >> 1;

    f32x4 o[2] = {};
#pragma unroll
    for (int s = 0; s < 2; ++s) {   // K=64 -> 2 k-steps of 32
        const float* hrow = &hsm[rt * 16 + m][s * 32 + kg * 8];
        float av[8];
#pragma unroll
        for (int j = 0; j < 8; ++j) av[j] = hrow[j];
        bf16x8 ahi, alo;
#pragma unroll
        for (int j = 0; j < 8; ++j) {
            const unsigned short hh = f2bf(av[j]);
            ahi[j] = (short)hh;
            alo[j] = (short)f2bf(av[j] - bf2f(hh));
        }
#pragma unroll
        for (int p = 0; p < 2; ++p) {
            const int nt = n0t + p * 2;
            const bf16x8 bh = *(const bf16x8*)&whi2[(s * 4 + nt) * 512 + lane * 8];
            const bf16x8 bl = *(const bf16x8*)&wlo2[(s * 4 + nt) * 512 + lane * 8];
            o[p] = __builtin_amdgcn_mfma_f32_16x16x32_bf16(ahi, bh, o[p], 0, 0, 0);
            o[p] = __builtin_amdgcn_mfma_f32_16x16x32_bf16(alo, bh, o[p], 0, 0, 0);
            o[p] = __builtin_amdgcn_mfma_f32_16x16x32_bf16(ahi, bl, o[p], 0, 0, 0);
        }
    }

    // C/D: col = lane&15 (= m, output channel within ntile), row = kg*4 + r
#pragma unroll
    for (int p = 0; p < 2; ++p) {
        const int nt = n0t + p * 2;
#pragma unroll
        for (int r = 0; r < 4; ++r) {
            const int lr   = rt * 16 + kg * 4 + r;
            const int orow = blockIdx.x * 32 + lr;
            if (orow < N)
                h2b[(size_t)orow * 64 + nt * 16 + m] = f2bf(o[p][r] * dsm[lr]);
        }
    }
}

// ---------------- layer 2: gather prescaled h2 + bias + log_softmax -> fp32 out ----

__global__ __launch_bounds__(256) void agg_l2(const unsigned short* __restrict__ B,
                                              const int* __restrict__ csr,
                                              const int2* __restrict__ rowptr,
                                              const float* __restrict__ dis,
                                              const float* __restrict__ b2,
                                              float* __restrict__ out, int N) {
    const int wid  = threadIdx.x >> 6;
    const int lane = threadIdx.x & 63;
    const int eg   = lane >> 3;
    const int co   = lane & 7;

    const int  row = blockIdx.x * 32 + wid * 8 + eg;
    const bool hr  = (row < N);

    const int2  rp = hr ? rowptr[row] : make_int2(0, 0);
    const float di = hr ? dis[row] : 0.f;

    float acc[8] = {};
    gather8i(B, csr, rp.x, rp.y, co, acc);

    if (!hr) return;

    uint4 us = *(const uint4*)&B[(size_t)row * 64 + co * 8];
    float bs[8];
    bf8_unpack(us, bs);
    float bb[8];
    *(float4*)&bb[0] = *(const float4*)&b2[co * 8];
    *(float4*)&bb[4] = *(const float4*)&b2[co * 8 + 4];

    float v[8];
#pragma unroll
    for (int i = 0; i < 8; i++) v[i] = (acc[i] + bs[i]) * di + bb[i];

    float m = v[0];
#pragma unroll
    for (int i = 1; i < 8; i++) m = fmaxf(m, v[i]);
#pragma unroll
    for (int off = 1; off <= 4; off <<= 1) m = fmaxf(m, __shfl_xor(m, off));
    float s = 0.f;
#pragma unroll
    for (int i = 0; i < 8; i++) s += __expf(v[i] - m);
#pragma unroll
    for (int off = 1; off <= 4; off <<= 1) s += __shfl_xor(s, off);
    float lse = m + __logf(s);

    float4 oa = make_float4(v[0] - lse, v[1] - lse, v[2] - lse, v[3] - lse);
    float4 ob = make_float4(v[4] - lse, v[5] - lse, v[6] - lse, v[7] - lse);
    *(float4*)&out[(size_t)row * 64 + co * 8]     = oa;
    *(float4*)&out[(size_t)row * 64 + co * 8 + 4] = ob;
}

// ---------------- launch ----------------

extern "C" void kernel_launch(void* const* d_in, const int* in_sizes, int n_in,
                              void* d_out, int out_size, void* d_ws, size_t ws_size,
                              hipStream_t stream) {
    const float* x   = (const float*)d_in[0];
    const int*   ei  = (const int*)d_in[1];
    const float* W1  = (const float*)d_in[2];
    const float* b1  = (const float*)d_in[3];
    const float* W2  = (const float*)d_in[4];
    const float* b2  = (const float*)d_in[5];
    float*       out = (float*)d_out;

    const int  N   = in_sizes[0] / 128;
    const int  E   = in_sizes[1] / 2;
    const int* src = ei;
    const int* dst = ei + E;

    int shift = 9;
    while (((N - 1) >> shift) >= 256) shift++;
    const int NBUCK = ((N - 1) >> shift) + 1;
    const int CAP   = ((E / NBUCK) * 3 / 2 + 255) & ~255;
    const int CAPC  = CAP + 8 * (1 << shift);   // edges + worst-case pad, per bucket

    auto align256 = [](size_t v) { return (v + 255) & ~(size_t)255; };
    char*           p        = (char*)d_ws;
    float*          dis      = (float*)p;          p += align256((size_t)N * 4);
    int2*           rowptr   = (int2*)p;           p += align256((size_t)N * 8);
    int*            bcur     = (int*)p;            p += align256(256 * 4);
    int*            csr      = (int*)p;            p += align256((size_t)NBUCK * CAPC * 4);
    int2*           bbuf     = (int2*)p;           p += align256((size_t)NBUCK * CAP * 8);
    unsigned short* xwb      = (unsigned short*)p; p += align256((size_t)(N + 1) * 64 * 2);
    unsigned short* h2b      = (unsigned short*)p; p += align256((size_t)(N + 1) * 64 * 2);
    unsigned short* whi1     = (unsigned short*)p; p += align256(128 * 64 * 2);
    unsigned short* wlo1     = (unsigned short*)p; p += align256(128 * 64 * 2);
    unsigned short* whi2     = (unsigned short*)p; p += align256(64 * 64 * 2);
    unsigned short* wlo2     = (unsigned short*)p; p += align256(64 * 64 * 2);

    prep_wfrag<<<1, 256, 0, stream>>>(W1, W2, whi1, wlo1, whi2, wlo2, bcur, xwb, h2b, N);
    passA<<<(E + PASSA_EDGES - 1) / PASSA_EDGES, 256, 0, stream>>>(src, dst, bcur, bbuf, E, CAP, shift);
    build_csr<<<NBUCK, 256, 0, stream>>>(bbuf, bcur, rowptr, dis, csr, N, CAP, CAPC, shift);

    gemm_mfma<128><<<(N + 63) / 64, 256, 0, stream>>>(x, whi1, wlo1, dis, xwb, N);
    // fused: gather(xwb) + relu + gemm2(MFMA, in-block) -> h2b  (hs round trip deleted)
    agg_l1f<<<(N + 31) / 32, 256, 0, stream>>>(xwb, csr, rowptr, dis, b1, whi2, wlo2, h2b, N);
    agg_l2<<<(N + 31) / 32, 256, 0, stream>>>(h2b, csr, rowptr, dis, b2, out, N);
}

// Round 14
// 232.631 us; speedup vs baseline: 1.4088x; 1.0170x over previous
//
#include <hip/hip_runtime.h>
#include <cstdint>
#include <cstddef>

#define PASSA_EDGES 2048

typedef __attribute__((ext_vector_type(8))) short bf16x8;   // 8 bf16 = 4 VGPR (MFMA A/B frag)
typedef __attribute__((ext_vector_type(4))) float f32x4;    // MFMA C/D frag

// ---------------- bf16 helpers ----------------

__device__ __forceinline__ unsigned short f2bf(float f) {  // RNE
    unsigned int u = __float_as_uint(f);
    u += 0x7FFFu + ((u >> 16) & 1u);
    return (unsigned short)(u >> 16);
}
__device__ __forceinline__ float bf2f(unsigned short h) {
    return __uint_as_float((unsigned int)h << 16);
}

// acc[8] += 8 bf16 (packed in uint4)  -- weight-free gather accumulate
__device__ __forceinline__ void bf8_acc(uint4 u, float* acc) {
    acc[0] += __uint_as_float(u.x << 16);
    acc[1] += __uint_as_float(u.x & 0xFFFF0000u);
    acc[2] += __uint_as_float(u.y << 16);
    acc[3] += __uint_as_float(u.y & 0xFFFF0000u);
    acc[4] += __uint_as_float(u.z << 16);
    acc[5] += __uint_as_float(u.z & 0xFFFF0000u);
    acc[6] += __uint_as_float(u.w << 16);
    acc[7] += __uint_as_float(u.w & 0xFFFF0000u);
}
__device__ __forceinline__ void bf8_unpack(uint4 u, float* v) {
    v[0] = __uint_as_float(u.x << 16);
    v[1] = __uint_as_float(u.x & 0xFFFF0000u);
    v[2] = __uint_as_float(u.y << 16);
    v[3] = __uint_as_float(u.y & 0xFFFF0000u);
    v[4] = __uint_as_float(u.z << 16);
    v[5] = __uint_as_float(u.z & 0xFFFF0000u);
    v[6] = __uint_as_float(u.w << 16);
    v[7] = __uint_as_float(u.w & 0xFFFF0000u);
}

// ---------------- pass A: bins image + FLAT coalesced writeout, PACKED bbuf --------
// Local counting sort into a 16KB LDS bins image (bucket-ordered), then a FLAT
// writeout (zero lane waste, bucket-run-contiguous destinations, no write
// amplification). R14: bbuf entries are PACKED ints: (src << shift) | (dst & mask)
// -- src < 2^(31-shift) holds (N=100k -> 17 bits, shift=9). Halves bbuf write
// traffic here and read traffic in build_csr's two passes.

__global__ __launch_bounds__(256) void passA(const int* __restrict__ src,
                                             const int* __restrict__ dst,
                                             int* __restrict__ bcur,
                                             int* __restrict__ bbuf, int E,
                                             int CAP, int shift) {
    __shared__ int2 bins[PASSA_EDGES];
    __shared__ int  cnt[256], off[256], cur[256], gbase[256];
    const int t    = threadIdx.x;
    const int e0   = blockIdx.x * PASSA_EDGES;
    const int n    = min(PASSA_EDGES, E - e0);
    const int mask = (1 << shift) - 1;

    cnt[t] = 0;
    __syncthreads();
    for (int i = t; i < n; i += 256) atomicAdd(&cnt[dst[e0 + i] >> shift], 1);
    __syncthreads();

    // 256-wide exclusive scan (Hillis-Steele)
    const int v = cnt[t];
    off[t] = v;
    __syncthreads();
    for (int o = 1; o < 256; o <<= 1) {
        int u = (t >= o) ? off[t - o] : 0;
        __syncthreads();
        off[t] += u;
        __syncthreads();
    }
    const int excl = off[t] - v;
    off[t] = excl;                    // own-slot rewrite, no race
    cur[t] = excl;
    if (v > 0) gbase[t] = t * CAP + atomicAdd(&bcur[t], v);
    __syncthreads();

    // local scatter: bins becomes bucket-ordered
    for (int i = t; i < n; i += 256) {
        const int d = dst[e0 + i];
        const int s = src[e0 + i];
        const int p = atomicAdd(&cur[d >> shift], 1);
        bins[p] = make_int2(s, d);
    }
    __syncthreads();

    // flat writeout: every lane active, bucket-run-contiguous destinations
    for (int i = t; i < n; i += 256) {
        const int2 pr = bins[i];
        const int  b  = pr.y >> shift;
        const int  q  = gbase[b] + (i - off[b]);
        if (q < (b + 1) * CAP) bbuf[q] = (pr.x << shift) | (pr.y & mask);
    }
}

// ---------------- build_csr: fused hist + LOCAL scan + scatter + pad + dis ---------
// Each bucket owns a fixed csr window of CAPC ints (>= CAP + 7*nodes worst-case
// padding); everything bucket-local: hist + local scan + scatter + pad fill + dis
// in ONE kernel. rowptr[node] = {csr start, iters=pdeg>>3}. All global writes land
// dense in the bucket window (R7/R9/R10: random scattered stores = 64B line each).
// R14: reads packed bbuf (local = pk & mask, src = pk >> shift).

__global__ __launch_bounds__(256) void build_csr(const int* __restrict__ bbuf,
                                                 const int* __restrict__ bcur,
                                                 int2* __restrict__ rowptr,
                                                 float* __restrict__ dis,
                                                 int* __restrict__ csr,
                                                 int N, int CAP, int CAPC, int shift) {
    __shared__ int cnt[1024];
    __shared__ int lcur[1024];
    __shared__ int psum[256];
    const int t     = threadIdx.x;
    const int b     = blockIdx.x;
    const int node0 = b << shift;
    const int nn    = min(1 << shift, N - node0);
    const int mask  = (1 << shift) - 1;

    for (int j = t; j < nn; j += 256) cnt[j] = 0;
    __syncthreads();

    const int start = b * CAP;
    const int end   = min(b * CAP + bcur[b], (b + 1) * CAP);
    for (int e = start + t; e < end; e += 256)
        atomicAdd(&cnt[bbuf[e] & mask], 1);
    __syncthreads();

    // local exclusive scan of 8-padded degrees (4 nodes/thread + 256-wide HS)
    int v[4];
    int s = 0;
#pragma unroll
    for (int i = 0; i < 4; i++) {
        const int j = t * 4 + i;
        v[i] = (j < nn) ? ((cnt[j] + 7) & ~7) : 0;
        s += v[i];
    }
    psum[t] = s;
    __syncthreads();
    for (int o = 1; o < 256; o <<= 1) {
        int u = (t >= o) ? psum[t - o] : 0;
        __syncthreads();
        psum[t] += u;
        __syncthreads();
    }
    int run = b * CAPC + psum[t] - s;
#pragma unroll
    for (int i = 0; i < 4; i++) {
        const int j = t * 4 + i;
        if (j < nn) {
            lcur[j] = run;
            rowptr[node0 + j] = make_int2(run, v[i] >> 3);
            dis[node0 + j]    = rsqrtf((float)(cnt[j] + 1));  // +1 self loop
            run += v[i];
        }
    }
    __syncthreads();

    // scatter into the bucket's dense csr window
    for (int e = start + t; e < end; e += 256) {
        const int pk = bbuf[e];
        const int p  = atomicAdd(&lcur[pk & mask], 1);
        csr[p] = pk >> shift;          // pk >= 0, arithmetic shr == logical
    }
    __syncthreads();

    // pad fill: lcur[j] = rowstart + true deg; fill to rowstart + pdeg with row N
    int base2 = b * CAPC + psum[t] - s;
#pragma unroll
    for (int i = 0; i < 4; i++) {
        const int j = t * 4 + i;
        if (j < nn) {
            const int rowend = base2 + v[i];
            for (int p = lcur[j]; p < rowend; ++p) csr[p] = N;  // zero-row pad
            base2 += v[i];
        }
    }
}

// ---------------- W fragment prep + init (fp32 W -> fragment-ordered bf16 hi/lo) ---
// B-frag layout for mfma_f32_16x16x32_bf16: lane&15 = out-col n, lane>>4 = k-octet,
// 8 contiguous k per lane. Stored so lane l of frag-block (kstep*4+nt) reads its
// 16 B contiguously at [(kstep*4+nt)*512 + l*8]. hi = RNE(w); lo = RNE(w - hi):
// Xhi*Whi + Xlo*Whi + Xhi*Wlo reproduces fp32 to ~2^-17 (lo*lo dropped).
// Also zeros bcur + the two pad rows (replaces 2 memset launches).

__global__ __launch_bounds__(256) void prep_wfrag(const float* __restrict__ W1,
                                                  const float* __restrict__ W2,
                                                  unsigned short* __restrict__ whi1,
                                                  unsigned short* __restrict__ wlo1,
                                                  unsigned short* __restrict__ whi2,
                                                  unsigned short* __restrict__ wlo2,
                                                  int* __restrict__ bcur,
                                                  unsigned short* __restrict__ xwb,
                                                  unsigned short* __restrict__ h2b,
                                                  int N) {
    bcur[threadIdx.x] = 0;
    if (threadIdx.x < 64) {
        xwb[(size_t)N * 64 + threadIdx.x] = 0;   // zero pad-row N (layer-1 table)
        h2b[(size_t)N * 64 + threadIdx.x] = 0;   // zero pad-row N (layer-2 table)
    }
    for (int e = threadIdx.x; e < 128 * 64; e += 256) {
        const int blk = e >> 9, l = (e >> 3) & 63, j = e & 7;
        const int k = (blk >> 2) * 32 + (l >> 4) * 8 + j;
        const int n = (blk & 3) * 16 + (l & 15);
        const float v = W1[k * 64 + n];
        const unsigned short h = f2bf(v);
        whi1[e] = h;
        wlo1[e] = f2bf(v - bf2f(h));
    }
    for (int e = threadIdx.x; e < 64 * 64; e += 256) {
        const int blk = e >> 9, l = (e >> 3) & 63, j = e & 7;
        const int k = (blk >> 2) * 32 + (l >> 4) * 8 + j;
        const int n = (blk & 3) * 16 + (l & 15);
        const float v = W2[k * 64 + n];
        const unsigned short h = f2bf(v);
        whi2[e] = h;
        wlo2[e] = f2bf(v - bf2f(h));
    }
}

// ---------------- MFMA GEMM: Yb[N x 64](bf16) = (X[N x K](f32) @ W) * dis[row] -----
// R14: NO LDS staging. The A-frag read is per-lane UNIQUE (lane (m,kg) reads 32
// contiguous bytes of row w*16+m) -- LDS bought zero reuse and cost 33.8KB
// (4 blocks/CU cap) + a barrier + an extra write/read pass. Direct global loads:
// kg0/kg1 (kg2/kg3) of one row cover full 64B lines; 4 fully-unrolled k-steps
// software-pipeline freely (no barrier). Numerics identical (same values, same
// MFMA order). dis[row] prescale in the epilogue (enables the weight-free csr).
// C/D: col = lane&15, row = (lane>>4)*4 + reg [m89-verified mapping].

template <int K>
__global__ __launch_bounds__(256) void gemm_mfma(const float* __restrict__ X,
                                                 const unsigned short* __restrict__ whi,
                                                 const unsigned short* __restrict__ wlo,
                                                 const float* __restrict__ dis,
                                                 unsigned short* __restrict__ Yb, int N) {
    const int tid  = threadIdx.x;
    const int row0 = blockIdx.x * 64;
    const int w = tid >> 6, l = tid & 63;
    const int m = l & 15, kg = l >> 4;

    const float* xrow = X + (size_t)min(row0 + w * 16 + m, N - 1) * K;

    f32x4 acc[4] = {};
#pragma unroll
    for (int s = 0; s < K / 32; ++s) {
        const float4 a0 = *(const float4*)(xrow + s * 32 + kg * 8);
        const float4 a1 = *(const float4*)(xrow + s * 32 + kg * 8 + 4);
        const float av[8] = {a0.x, a0.y, a0.z, a0.w, a1.x, a1.y, a1.z, a1.w};
        bf16x8 ahi, alo;
#pragma unroll
        for (int j = 0; j < 8; ++j) {
            const unsigned short h = f2bf(av[j]);
            ahi[j] = (short)h;
            alo[j] = (short)f2bf(av[j] - bf2f(h));
        }
#pragma unroll
        for (int nt = 0; nt < 4; ++nt) {
            const bf16x8 bh = *(const bf16x8*)&whi[(s * 4 + nt) * 512 + l * 8];
            const bf16x8 bl = *(const bf16x8*)&wlo[(s * 4 + nt) * 512 + l * 8];
            acc[nt] = __builtin_amdgcn_mfma_f32_16x16x32_bf16(ahi, bh, acc[nt], 0, 0, 0);
            acc[nt] = __builtin_amdgcn_mfma_f32_16x16x32_bf16(alo, bh, acc[nt], 0, 0, 0);
            acc[nt] = __builtin_amdgcn_mfma_f32_16x16x32_bf16(ahi, bl, acc[nt], 0, 0, 0);
        }
    }

    float dv[4];
#pragma unroll
    for (int r = 0; r < 4; ++r)
        dv[r] = dis[min(row0 + w * 16 + kg * 4 + r, N - 1)];

#pragma unroll
    for (int nt = 0; nt < 4; ++nt)
#pragma unroll
        for (int r = 0; r < 4; ++r) {
            const int row = row0 + w * 16 + kg * 4 + r;
            if (row < N) Yb[(size_t)row * 64 + nt * 16 + m] = f2bf(acc[nt][r] * dv[r]);
        }
}

// ---------------- weight-free oct-row gather: 8 rows/wave, group-per-row -----------
// Slabs 8-padded; each lane reads its group's 8 src indices as 2 x int4 (32 B,
// broadcast across the 8 group lanes) then 8 independent prescaled-B row loads.
// Pad entries index zero-row N (contribute 0). Next chunk prefetched one iteration
// ahead; groups exit independently. Fabric-throughput-bound (~6 TB/s aggregate
// random 128B rows) -- near ceiling, left as-is.

__device__ __forceinline__ void gather8i(const unsigned short* __restrict__ B,
                                         const int* __restrict__ csr,
                                         int s0, int iters, int co, float* acc) {
    const int4* cs = (const int4*)(csr + s0);   // 32B-aligned (s0 % 8 == 0)
    int4 c0 = make_int4(0, 0, 0, 0), c1 = c0;
    if (iters > 0) { c0 = cs[0]; c1 = cs[1]; }
    for (int it = 0; it < iters; ++it) {
        const int nb = min(it + 1, iters - 1) * 2;   // prefetch next chunk (clamped)
        int4 n0 = cs[nb], n1 = cs[nb + 1];
        uint4 u0 = *(const uint4*)&B[(size_t)c0.x * 64 + co * 8];
        uint4 u1 = *(const uint4*)&B[(size_t)c0.y * 64 + co * 8];
        uint4 u2 = *(const uint4*)&B[(size_t)c0.z * 64 + co * 8];
        uint4 u3 = *(const uint4*)&B[(size_t)c0.w * 64 + co * 8];
        uint4 u4 = *(const uint4*)&B[(size_t)c1.x * 64 + co * 8];
        uint4 u5 = *(const uint4*)&B[(size_t)c1.y * 64 + co * 8];
        uint4 u6 = *(const uint4*)&B[(size_t)c1.z * 64 + co * 8];
        uint4 u7 = *(const uint4*)&B[(size_t)c1.w * 64 + co * 8];
        bf8_acc(u0, acc);
        bf8_acc(u1, acc);
        bf8_acc(u2, acc);
        bf8_acc(u3, acc);
        bf8_acc(u4, acc);
        bf8_acc(u5, acc);
        bf8_acc(u6, acc);
        bf8_acc(u7, acc);
        c0 = n0; c1 = n1;
    }
}

// ---------------- layer 1 FUSED: gather + relu + in-block MFMA gemm2 -> h2b bf16 ---
// h2[r] = h[r] @ W2 is ROW-WISE, so it fuses into agg_l1 legally (each block owns
// 32 complete rows). Phase 1: gather + self + bias + relu -> h staged in LDS (f32,
// exact). Phase 2: 8 output tiles (2 row-tiles x 4 ntiles) over 4 waves, same
// split-bf16 3-MFMA recipe + dis prescale as gemm_mfma. Deletes the hs 51MB HBM
// round trip and the gemm<64> launch.

__global__ __launch_bounds__(256) void agg_l1f(const unsigned short* __restrict__ B,
                                               const int* __restrict__ csr,
                                               const int2* __restrict__ rowptr,
                                               const float* __restrict__ dis,
                                               const float* __restrict__ b1,
                                               const unsigned short* __restrict__ whi2,
                                               const unsigned short* __restrict__ wlo2,
                                               unsigned short* __restrict__ h2b, int N) {
    __shared__ float hsm[32][68];   // 32 rows x 64 ch, +4 pad (bank stride 4m -> 2-way, free)
    __shared__ float dsm[32];
    const int wid  = threadIdx.x >> 6;
    const int lane = threadIdx.x & 63;
    const int eg   = lane >> 3;
    const int co   = lane & 7;
    const int lrow = wid * 8 + eg;

    const int  row = blockIdx.x * 32 + lrow;   // group eg of wave wid owns this row
    const bool hr  = (row < N);

    const int2  rp = hr ? rowptr[row] : make_int2(0, 0);
    const float di = hr ? dis[row] : 0.f;

    float acc[8] = {};
    gather8i(B, csr, rp.x, rp.y, co, acc);

    float h[8] = {};
    if (hr) {
        uint4 us = *(const uint4*)&B[(size_t)row * 64 + co * 8];
        float bs[8];
        bf8_unpack(us, bs);
        float bb[8];
        *(float4*)&bb[0] = *(const float4*)&b1[co * 8];
        *(float4*)&bb[4] = *(const float4*)&b1[co * 8 + 4];
#pragma unroll
        for (int i = 0; i < 8; i++)
            h[i] = fmaxf((acc[i] + bs[i]) * di + bb[i], 0.f);
    }
    *(float4*)&hsm[lrow][co * 8]     = make_float4(h[0], h[1], h[2], h[3]);
    *(float4*)&hsm[lrow][co * 8 + 4] = make_float4(h[4], h[5], h[6], h[7]);
    if (co == 0) dsm[lrow] = di;
    __syncthreads();

    // ---- in-block gemm2: wave wid handles row-tile rt = wid&1, ntiles {wid>>1, (wid>>1)+2}
    const int m  = lane & 15, kg = lane >> 4;
    const int rt = wid & 1;
    const int n0t = wid >> 1;

    f32x4 o[2] = {};
#pragma unroll
    for (int s = 0; s < 2; ++s) {   // K=64 -> 2 k-steps of 32
        const float* hrow = &hsm[rt * 16 + m][s * 32 + kg * 8];
        float av[8];
#pragma unroll
        for (int j = 0; j < 8; ++j) av[j] = hrow[j];
        bf16x8 ahi, alo;
#pragma unroll
        for (int j = 0; j < 8; ++j) {
            const unsigned short hh = f2bf(av[j]);
            ahi[j] = (short)hh;
            alo[j] = (short)f2bf(av[j] - bf2f(hh));
        }
#pragma unroll
        for (int p = 0; p < 2; ++p) {
            const int nt = n0t + p * 2;
            const bf16x8 bh = *(const bf16x8*)&whi2[(s * 4 + nt) * 512 + lane * 8];
            const bf16x8 bl = *(const bf16x8*)&wlo2[(s * 4 + nt) * 512 + lane * 8];
            o[p] = __builtin_amdgcn_mfma_f32_16x16x32_bf16(ahi, bh, o[p], 0, 0, 0);
            o[p] = __builtin_amdgcn_mfma_f32_16x16x32_bf16(alo, bh, o[p], 0, 0, 0);
            o[p] = __builtin_amdgcn_mfma_f32_16x16x32_bf16(ahi, bl, o[p], 0, 0, 0);
        }
    }

    // C/D: col = lane&15 (= m, output channel within ntile), row = kg*4 + r
#pragma unroll
    for (int p = 0; p < 2; ++p) {
        const int nt = n0t + p * 2;
#pragma unroll
        for (int r = 0; r < 4; ++r) {
            const int lr   = rt * 16 + kg * 4 + r;
            const int orow = blockIdx.x * 32 + lr;
            if (orow < N)
                h2b[(size_t)orow * 64 + nt * 16 + m] = f2bf(o[p][r] * dsm[lr]);
        }
    }
}

// ---------------- layer 2: gather prescaled h2 + bias + log_softmax -> fp32 out ----

__global__ __launch_bounds__(256) void agg_l2(const unsigned short* __restrict__ B,
                                              const int* __restrict__ csr,
                                              const int2* __restrict__ rowptr,
                                              const float* __restrict__ dis,
                                              const float* __restrict__ b2,
                                              float* __restrict__ out, int N) {
    const int wid  = threadIdx.x >> 6;
    const int lane = threadIdx.x & 63;
    const int eg   = lane >> 3;
    const int co   = lane & 7;

    const int  row = blockIdx.x * 32 + wid * 8 + eg;
    const bool hr  = (row < N);

    const int2  rp = hr ? rowptr[row] : make_int2(0, 0);
    const float di = hr ? dis[row] : 0.f;

    float acc[8] = {};
    gather8i(B, csr, rp.x, rp.y, co, acc);

    if (!hr) return;

    uint4 us = *(const uint4*)&B[(size_t)row * 64 + co * 8];
    float bs[8];
    bf8_unpack(us, bs);
    float bb[8];
    *(float4*)&bb[0] = *(const float4*)&b2[co * 8];
    *(float4*)&bb[4] = *(const float4*)&b2[co * 8 + 4];

    float v[8];
#pragma unroll
    for (int i = 0; i < 8; i++) v[i] = (acc[i] + bs[i]) * di + bb[i];

    float m = v[0];
#pragma unroll
    for (int i = 1; i < 8; i++) m = fmaxf(m, v[i]);
#pragma unroll
    for (int off = 1; off <= 4; off <<= 1) m = fmaxf(m, __shfl_xor(m, off));
    float s = 0.f;
#pragma unroll
    for (int i = 0; i < 8; i++) s += __expf(v[i] - m);
#pragma unroll
    for (int off = 1; off <= 4; off <<= 1) s += __shfl_xor(s, off);
    float lse = m + __logf(s);

    float4 oa = make_float4(v[0] - lse, v[1] - lse, v[2] - lse, v[3] - lse);
    float4 ob = make_float4(v[4] - lse, v[5] - lse, v[6] - lse, v[7] - lse);
    *(float4*)&out[(size_t)row * 64 + co * 8]     = oa;
    *(float4*)&out[(size_t)row * 64 + co * 8 + 4] = ob;
}

// ---------------- launch ----------------

extern "C" void kernel_launch(void* const* d_in, const int* in_sizes, int n_in,
                              void* d_out, int out_size, void* d_ws, size_t ws_size,
                              hipStream_t stream) {
    const float* x   = (const float*)d_in[0];
    const int*   ei  = (const int*)d_in[1];
    const float* W1  = (const float*)d_in[2];
    const float* b1  = (const float*)d_in[3];
    const float* W2  = (const float*)d_in[4];
    const float* b2  = (const float*)d_in[5];
    float*       out = (float*)d_out;

    const int  N   = in_sizes[0] / 128;
    const int  E   = in_sizes[1] / 2;
    const int* src = ei;
    const int* dst = ei + E;

    int shift = 9;
    while (((N - 1) >> shift) >= 256) shift++;
    const int NBUCK = ((N - 1) >> shift) + 1;
    const int CAP   = ((E / NBUCK) * 3 / 2 + 255) & ~255;
    const int CAPC  = CAP + 8 * (1 << shift);   // edges + worst-case pad, per bucket

    auto align256 = [](size_t v) { return (v + 255) & ~(size_t)255; };
    char*           p        = (char*)d_ws;
    float*          dis      = (float*)p;          p += align256((size_t)N * 4);
    int2*           rowptr   = (int2*)p;           p += align256((size_t)N * 8);
    int*            bcur     = (int*)p;            p += align256(256 * 4);
    int*            csr      = (int*)p;            p += align256((size_t)NBUCK * CAPC * 4);
    int*            bbuf     = (int*)p;            p += align256((size_t)NBUCK * CAP * 4);
    unsigned short* xwb      = (unsigned short*)p; p += align256((size_t)(N + 1) * 64 * 2);
    unsigned short* h2b      = (unsigned short*)p; p += align256((size_t)(N + 1) * 64 * 2);
    unsigned short* whi1     = (unsigned short*)p; p += align256(128 * 64 * 2);
    unsigned short* wlo1     = (unsigned short*)p; p += align256(128 * 64 * 2);
    unsigned short* whi2     = (unsigned short*)p; p += align256(64 * 64 * 2);
    unsigned short* wlo2     = (unsigned short*)p; p += align256(64 * 64 * 2);

    prep_wfrag<<<1, 256, 0, stream>>>(W1, W2, whi1, wlo1, whi2, wlo2, bcur, xwb, h2b, N);
    passA<<<(E + PASSA_EDGES - 1) / PASSA_EDGES, 256, 0, stream>>>(src, dst, bcur, bbuf, E, CAP, shift);
    build_csr<<<NBUCK, 256, 0, stream>>>(bbuf, bcur, rowptr, dis, csr, N, CAP, CAPC, shift);

    gemm_mfma<128><<<(N + 63) / 64, 256, 0, stream>>>(x, whi1, wlo1, dis, xwb, N);
    // fused: gather(xwb) + relu + gemm2(MFMA, in-block) -> h2b  (hs round trip deleted)
    agg_l1f<<<(N + 31) / 32, 256, 0, stream>>>(xwb, csr, rowptr, dis, b1, whi2, wlo2, h2b, N);
    agg_l2<<<(N + 31) / 32, 256, 0, stream>>>(h2b, csr, rowptr, dis, b2, out, N);
}